// Round 1
// 429.951 us; speedup vs baseline: 1.0561x; 1.0561x over previous
//
#include <hip/hip_runtime.h>
#include <math.h>

#define SCALE_C 0.08838834764831845f  // 1/sqrt(128)
#define INV_BETA 50.0f
#define STEP63 (2.0f / 63.0f)

typedef short bf16x8 __attribute__((ext_vector_type(8)));
typedef float f32x4 __attribute__((ext_vector_type(4)));

// align_corners bilinear coefficients for 32 -> 64 (src = t*31/63)
__device__ __forceinline__ void interp_coef32(int t, int& i0, int& i1, float& w) {
    float s = (float)(t * 31) / 63.0f;
    i0 = (int)floorf(s);
    if (i0 > 31) i0 = 31;
    i1 = i0 + 1;
    if (i1 > 31) i1 = 31;
    w = s - (float)i0;
}

// ---------------------------------------------------------------------------
// corr_c: [b,1024,1024] = f0c^T f1c / sqrt(128). 64x64 tile per block.
// ---------------------------------------------------------------------------
__global__ __launch_bounds__(256) void k_corr_c(const float* __restrict__ f0c,
                                                const float* __restrict__ f1c,
                                                float* __restrict__ ws) {
    __shared__ float As[16][64];
    __shared__ float Bs[16][64];
    const int b = blockIdx.z;
    const int m0 = blockIdx.y * 64, n0 = blockIdx.x * 64;
    const float* A  = f0c + (long long)b * 131072;
    const float* Bp = f1c + (long long)b * 131072;
    const int tid = threadIdx.x;
    const int tx = tid & 15, ty = tid >> 4;
    const int lk = tid >> 4;
    const int lc = (tid & 15) * 4;
    float acc[4][4] = {{0.f}};
    for (int k0 = 0; k0 < 128; k0 += 16) {
        *(float4*)&As[lk][lc] = *(const float4*)&A[(k0 + lk) * 1024 + m0 + lc];
        *(float4*)&Bs[lk][lc] = *(const float4*)&Bp[(k0 + lk) * 1024 + n0 + lc];
        __syncthreads();
#pragma unroll
        for (int kk = 0; kk < 16; ++kk) {
            float4 a4 = *(float4*)&As[kk][ty * 4];
            float4 b4 = *(float4*)&Bs[kk][tx * 4];
            float av[4] = {a4.x, a4.y, a4.z, a4.w};
            float bv[4] = {b4.x, b4.y, b4.z, b4.w};
#pragma unroll
            for (int i = 0; i < 4; ++i)
#pragma unroll
                for (int j = 0; j < 4; ++j)
                    acc[i][j] = fmaf(av[i], bv[j], acc[i][j]);
        }
        __syncthreads();
    }
#pragma unroll
    for (int i = 0; i < 4; ++i) {
        float4 w4 = make_float4(acc[i][0] * SCALE_C, acc[i][1] * SCALE_C,
                                acc[i][2] * SCALE_C, acc[i][3] * SCALE_C);
        *(float4*)&ws[(long long)b * 1048576 + (long long)(m0 + ty * 4 + i) * 1024 + n0 + tx * 4] = w4;
    }
}

// ---------------------------------------------------------------------------
// k_split: fp32 [mat][128 k][4096 pix] -> bf16 hi/lo planes [mat][pix][128 k].
// hi = RNE bf16 of x, lo = RNE bf16 of (x - hi). Planes staged in out buffer
// (trans_features region, rewritten later by k_copy_trans).
// ---------------------------------------------------------------------------
__global__ __launch_bounds__(256) void k_split(const float* __restrict__ f0f,
                                               const float* __restrict__ f1f,
                                               unsigned short* __restrict__ hi,
                                               unsigned short* __restrict__ lo) {
    __shared__ unsigned int t[64 * 132];   // packed (hi | lo<<16), [pix][k] stride 132
    const int m = blockIdx.y;              // plane: 0,1 = f0f b0,b1; 2,3 = f1f b0,b1
    const int pt = blockIdx.x;             // pixel tile (64 pix)
    const float* src = ((m >> 1) ? f1f : f0f) + (size_t)(m & 1) * 524288 + pt * 64;
    const int tid = threadIdx.x;
#pragma unroll
    for (int p = 0; p < 8; ++p) {
        int k = p * 16 + (tid >> 4);
        int px = (tid & 15) * 4;
        float4 v = *(const float4*)&src[(size_t)k * 4096 + px];
        float vv[4] = {v.x, v.y, v.z, v.w};
#pragma unroll
        for (int j = 0; j < 4; ++j) {
            float x = vv[j];
            unsigned int u = __float_as_uint(x);
            unsigned int h = (u + 0x7FFFu + ((u >> 16) & 1u)) >> 16;     // RNE bf16
            float r = x - __uint_as_float(h << 16);                      // exact
            unsigned int ur = __float_as_uint(r);
            unsigned int l2 = (ur + 0x7FFFu + ((ur >> 16) & 1u)) >> 16;  // RNE bf16
            t[(px + j) * 132 + k] = h | (l2 << 16);
        }
    }
    __syncthreads();
    const int row = tid >> 2, ks = (tid & 3) * 32;
    size_t obase = ((size_t)m * 4096 + (size_t)pt * 64 + row) * 128 + ks;
#pragma unroll
    for (int c = 0; c < 4; ++c) {
        unsigned int u[8];
        *(uint4*)&u[0] = *(const uint4*)&t[row * 132 + ks + c * 8];
        *(uint4*)&u[4] = *(const uint4*)&t[row * 132 + ks + c * 8 + 4];
        uint4 ho, lw;
        ho.x = (u[0] & 0xFFFFu) | (u[1] << 16);
        ho.y = (u[2] & 0xFFFFu) | (u[3] << 16);
        ho.z = (u[4] & 0xFFFFu) | (u[5] << 16);
        ho.w = (u[6] & 0xFFFFu) | (u[7] << 16);
        lw.x = (u[0] >> 16) | (u[1] & 0xFFFF0000u);
        lw.y = (u[2] >> 16) | (u[3] & 0xFFFF0000u);
        lw.z = (u[4] >> 16) | (u[5] & 0xFFFF0000u);
        lw.w = (u[6] >> 16) | (u[7] & 0xFFFF0000u);
        *(uint4*)&hi[obase + c * 8] = ho;
        *(uint4*)&lo[obase + c * 8] = lw;
    }
}

// ---------------------------------------------------------------------------
// k_fused2 (MFMA version): 128x128 tile of the 4096x4096 GEMM (K=128) via
// split-bf16 3-pass mfma_f32_16x16x32_bf16. 4 waves, each owns a 64x64
// sub-tile (wr=wv>>1 row-half, wc=wv&1 col-half) as 4x4 fragments of 16x16.
// Fragments load straight from the pre-transposed hi/lo planes (no LDS
// staging, no GEMM barriers). LDS holds only the transposed coarse-upsample
// table t2[pair][x1][xc0] (33.8 KB -> lower LDS than before).
// C/D fragment layout: col = lane&15, row = (lane>>4)*4 + reg.
// parts layout unchanged (k_flow untouched).
// ---------------------------------------------------------------------------
__global__ __launch_bounds__(256, 3) void k_fused2(const unsigned short* __restrict__ planes,
                                                   const float* __restrict__ cws,
                                                   float* __restrict__ c_out,
                                                   float* __restrict__ cf_out,
                                                   float* __restrict__ parts) {
    __shared__ __attribute__((aligned(16))) float smem[8448];   // t2[4][64][33]; aliased by pred4
    const int b = blockIdx.z, by = blockIdx.y, bx = blockIdx.x;
    const int tid = threadIdx.x;
    const int wv = tid >> 6, lane = tid & 63;
    const int lr = lane & 15, lq = lane >> 4;
    const int wr = wv >> 1, wc = wv & 1;

    // ---- build t2: y0/y1/x1-interpolated coarse corr, xc0 left coarse ----
    {
        const float* Cc = cws + (size_t)b * 1048576;
        for (int e = tid; e < 8192; e += 256) {
            int pair = e >> 11, rem = e & 2047;
            int xc0 = rem >> 6, x1 = rem & 63;
            int s0 = pair >> 1, s1 = pair & 1;
            int ya, yb; float wy0; interp_coef32(2 * by + s0, ya, yb, wy0);
            int za, zb; float wy1; interp_coef32(2 * bx + s1, za, zb, wy1);
            int xa, xb; float wx1; interp_coef32(x1, xa, xb, wx1);
            const float* r0 = Cc + (size_t)(ya * 32 + xc0) * 1024;
            const float* r1 = Cc + (size_t)(yb * 32 + xc0) * 1024;
            float g0 = (r0[za * 32 + xa] * (1.f - wy1) + r0[zb * 32 + xa] * wy1) * (1.f - wy0)
                     + (r1[za * 32 + xa] * (1.f - wy1) + r1[zb * 32 + xa] * wy1) * wy0;
            float g1 = (r0[za * 32 + xb] * (1.f - wy1) + r0[zb * 32 + xb] * wy1) * (1.f - wy0)
                     + (r1[za * 32 + xb] * (1.f - wy1) + r1[zb * 32 + xb] * wy1) * wy0;
            smem[(pair * 64 + x1) * 33 + xc0] = g0 * (1.f - wx1) + g1 * wx1;
        }
    }

    // ---- split-bf16 MFMA GEMM (no LDS involved) ----
    const unsigned short* Ah = planes + (size_t)b * 524288       + (size_t)(by * 128 + wr * 64) * 128;
    const unsigned short* Bh = planes + (size_t)(2 + b) * 524288 + (size_t)(bx * 128 + wc * 64) * 128;
    f32x4 acc[4][4];
#pragma unroll
    for (int i = 0; i < 4; ++i)
#pragma unroll
        for (int j = 0; j < 4; ++j) acc[i][j] = (f32x4){0.f, 0.f, 0.f, 0.f};

#pragma unroll 1
    for (int kc = 0; kc < 4; ++kc) {
        const int ko = kc * 32 + lq * 8;
        bf16x8 ah[4], al[4], bh[4], bl[4];
#pragma unroll
        for (int t = 0; t < 4; ++t) {
            const unsigned short* pa = Ah + (size_t)(t * 16 + lr) * 128 + ko;
            const unsigned short* pb = Bh + (size_t)(t * 16 + lr) * 128 + ko;
            ah[t] = *(const bf16x8*)pa;
            al[t] = *(const bf16x8*)(pa + 2097152);   // lo planes follow hi planes
            bh[t] = *(const bf16x8*)pb;
            bl[t] = *(const bf16x8*)(pb + 2097152);
        }
#pragma unroll
        for (int ni = 0; ni < 4; ++ni)
#pragma unroll
            for (int mi = 0; mi < 4; ++mi) {
                f32x4 a = acc[mi][ni];
                a = __builtin_amdgcn_mfma_f32_16x16x32_bf16(ah[mi], bh[ni], a, 0, 0, 0);
                a = __builtin_amdgcn_mfma_f32_16x16x32_bf16(al[mi], bh[ni], a, 0, 0, 0);
                a = __builtin_amdgcn_mfma_f32_16x16x32_bf16(ah[mi], bl[ni], a, 0, 0, 0);
                acc[mi][ni] = a;
            }
    }

    __syncthreads();   // t2 fully built before any epilogue read

    // ---- epilogue: x0-interp of coarse + combine ----
#pragma unroll
    for (int mi = 0; mi < 4; ++mi)
#pragma unroll
        for (int dr = 0; dr < 4; ++dr) {
            int x0 = mi * 16 + lq * 4 + dr;
            float s = (float)(x0 * 31) / 63.0f;
            int i0 = (int)s;
            float w = s - (float)i0;
            int i1 = i0 + 1; if (i1 > 31) i1 = 31;
#pragma unroll
            for (int ni = 0; ni < 4; ++ni) {
                const float* t2 = &smem[(wv * 64 + ni * 16 + lr) * 33];
                float up = t2[i0] * (1.f - w) + t2[i1] * w;
                acc[mi][ni][dr] = (acc[mi][ni][dr] * SCALE_C + up) * 0.5f;
            }
        }

    // ---- stores: c scalar (cols strided), c_flip float4 (dr contiguous) ----
    const int rowbase = by * 128 + wr * 64, colbase = bx * 128 + wc * 64;
    {
        size_t cb = ((size_t)b << 24) + (size_t)rowbase * 4096 + colbase;
        size_t fb = ((size_t)b << 24) + (size_t)colbase * 4096 + rowbase;
#pragma unroll
        for (int mi = 0; mi < 4; ++mi) {
#pragma unroll
            for (int dr = 0; dr < 4; ++dr) {
                int ro = mi * 16 + lq * 4 + dr;
#pragma unroll
                for (int ni = 0; ni < 4; ++ni)
                    c_out[cb + (size_t)ro * 4096 + ni * 16 + lr] = acc[mi][ni][dr];
            }
#pragma unroll
            for (int ni = 0; ni < 4; ++ni) {
                int co = ni * 16 + lr;
                *(float4*)&cf_out[fb + (size_t)co * 4096 + mi * 16 + lq * 4] =
                    make_float4(acc[mi][ni][0], acc[mi][ni][1], acc[mi][ni][2], acc[mi][ni][3]);
            }
        }
    }

    // ---- softmax partials ----
    float4* pred4 = (float4*)smem;
    float4* parts4 = (float4*)parts;
    __syncthreads();   // t2 reads done; reuse LDS as pred4

    // c-direction: per row, reduce over this wave's 64 cols (lanes sharing lq)
    {
        float yn1 = -1.f + (float)(2 * bx + wc) * STEP63;
#pragma unroll
        for (int mi = 0; mi < 4; ++mi)
#pragma unroll
            for (int dr = 0; dr < 4; ++dr) {
                float m = fmaxf(fmaxf(acc[mi][0][dr], acc[mi][1][dr]),
                                fmaxf(acc[mi][2][dr], acc[mi][3][dr]));
                m = fmaxf(m, __shfl_xor(m, 1, 64));
                m = fmaxf(m, __shfl_xor(m, 2, 64));
                m = fmaxf(m, __shfl_xor(m, 4, 64));
                m = fmaxf(m, __shfl_xor(m, 8, 64));
                float l = 0.f, sx = 0.f;
#pragma unroll
                for (int ni = 0; ni < 4; ++ni) {
                    float e = __expf((acc[mi][ni][dr] - m) * INV_BETA);
                    l += e;
                    sx += e * (-1.f + (float)(ni * 16 + lr) * STEP63);
                }
                l += __shfl_xor(l, 1, 64);  sx += __shfl_xor(sx, 1, 64);
                l += __shfl_xor(l, 2, 64);  sx += __shfl_xor(sx, 2, 64);
                l += __shfl_xor(l, 4, 64);  sx += __shfl_xor(sx, 4, 64);
                l += __shfl_xor(l, 8, 64);  sx += __shfl_xor(sx, 8, 64);
                if (lr == 0)
                    pred4[wc * 128 + wr * 64 + mi * 16 + lq * 4 + dr] = make_float4(m, l, sx, yn1 * l);
            }
    }
    __syncthreads();
    if (tid < 128) {
        float4 h0 = pred4[tid], h1 = pred4[128 + tid];
        float M = fmaxf(h0.x, h1.x);
        float s0 = __expf((h0.x - M) * INV_BETA);
        float s1 = __expf((h1.x - M) * INV_BETA);
        parts4[((size_t)b * 4096 + by * 128 + tid) * 32 + bx] =
            make_float4(M, h0.y * s0 + h1.y * s1, h0.z * s0 + h1.z * s1, h0.w * s0 + h1.w * s1);
    }
    __syncthreads();

    // f-direction: per col, reduce over this wave's 64 rows (lanes sharing lr)
    {
        float yn0 = -1.f + (float)(2 * by + wr) * STEP63;
#pragma unroll
        for (int ni = 0; ni < 4; ++ni) {
            float m = acc[0][ni][0];
#pragma unroll
            for (int mi = 0; mi < 4; ++mi)
#pragma unroll
                for (int dr = 0; dr < 4; ++dr) m = fmaxf(m, acc[mi][ni][dr]);
            m = fmaxf(m, __shfl_xor(m, 16, 64));
            m = fmaxf(m, __shfl_xor(m, 32, 64));
            float l = 0.f, sx = 0.f;
#pragma unroll
            for (int mi = 0; mi < 4; ++mi)
#pragma unroll
                for (int dr = 0; dr < 4; ++dr) {
                    float e = __expf((acc[mi][ni][dr] - m) * INV_BETA);
                    l += e;
                    sx += e * (-1.f + (float)(mi * 16 + lq * 4 + dr) * STEP63);
                }
            l += __shfl_xor(l, 16, 64);  sx += __shfl_xor(sx, 16, 64);
            l += __shfl_xor(l, 32, 64);  sx += __shfl_xor(sx, 32, 64);
            if (lq == 0)
                pred4[wr * 128 + wc * 64 + ni * 16 + lr] = make_float4(m, l, sx, yn0 * l);
        }
    }
    __syncthreads();
    if (tid < 128) {
        float4 h0 = pred4[tid], h1 = pred4[128 + tid];
        float M = fmaxf(h0.x, h1.x);
        float s0 = __expf((h0.x - M) * INV_BETA);
        float s1 = __expf((h1.x - M) * INV_BETA);
        parts4[262144 + ((size_t)b * 4096 + bx * 128 + tid) * 32 + by] =
            make_float4(M, h0.y * s0 + h1.y * s1, h0.z * s0 + h1.z * s1, h0.w * s0 + h1.w * s1);
    }
}

// ---------------------------------------------------------------------------
// k_flow: merge 32 partials per row -> flow values. One wave per row.
// ---------------------------------------------------------------------------
__global__ __launch_bounds__(256) void k_flow(const float* __restrict__ parts,
                                              float* __restrict__ flow,
                                              float* __restrict__ flowf) {
    const int row = blockIdx.x * 4 + (threadIdx.x >> 6);
    const int lane = threadIdx.x & 63;
    const float4* p4 = (const float4*)parts + (long long)row * 32;
    float m = -1e30f, l = 0.f, sx = 0.f, sy = 0.f;
    if (lane < 32) { float4 v = p4[lane]; m = v.x; l = v.y; sx = v.z; sy = v.w; }
    float M = m;
#pragma unroll
    for (int off = 1; off < 64; off <<= 1) M = fmaxf(M, __shfl_xor(M, off, 64));
    float s = __expf((m - M) * INV_BETA);
    l *= s; sx *= s; sy *= s;
#pragma unroll
    for (int off = 1; off < 64; off <<= 1) {
        l += __shfl_xor(l, off, 64);
        sx += __shfl_xor(sx, off, 64);
        sy += __shfl_xor(sy, off, 64);
    }
    if (lane == 0) {
        float gx = sx / l, gy = sy / l;
        float mx = (gx + 1.f) * 31.5f, my = (gy + 1.f) * 31.5f;
        int dir = row >> 13, b = (row >> 12) & 1, p = row & 4095;
        float* o = dir ? flowf : flow;
        o[(long long)b * 8192 + p] = mx - (float)(p & 63);
        o[(long long)b * 8192 + 4096 + p] = my - (float)(p >> 6);
    }
}

// ---------------------------------------------------------------------------
// trans_features = stack([f0f, f1f], axis=1)
// ---------------------------------------------------------------------------
__global__ void k_copy_trans(const float* __restrict__ f0f, const float* __restrict__ f1f,
                             float* __restrict__ out1) {
    int idx = blockIdx.x * 256 + threadIdx.x;
    int bv = idx >> 17;
    int r = idx & 131071;
    int b = bv >> 1, v = bv & 1;
    const float4* src = (const float4*)(v ? f1f : f0f) + (long long)b * 131072 + r;
    ((float4*)out1)[idx] = *src;
}

// ---------------------------------------------------------------------------
// trans_features_coarse: bilinear 32->64 of stacked feat_c
// ---------------------------------------------------------------------------
__global__ void k_coarse(const float* __restrict__ f0c, const float* __restrict__ f1c,
                         float* __restrict__ out2) {
    int idx = blockIdx.x * 256 + threadIdx.x;
    int x = idx & 63, y = (idx >> 6) & 63, ch = (idx >> 12) & 127;
    int v = (idx >> 19) & 1, b = idx >> 20;
    int iy0, iy1; float wy; interp_coef32(y, iy0, iy1, wy);
    int ix0, ix1; float wx; interp_coef32(x, ix0, ix1, wx);
    const float* src = (v ? f1c : f0c) + (long long)(b * 128 + ch) * 1024;
    float a  = src[iy0 * 32 + ix0] * (1.f - wy) + src[iy1 * 32 + ix0] * wy;
    float c2 = src[iy0 * 32 + ix1] * (1.f - wy) + src[iy1 * 32 + ix1] * wy;
    out2[idx] = a * (1.f - wx) + c2 * wx;
}

// ========================= fallback path (round-1) =========================
__global__ __launch_bounds__(256) void k_fused_fb(const float* __restrict__ f0f,
                                                  const float* __restrict__ f1f,
                                                  const float* __restrict__ cws,
                                                  float* __restrict__ c_out,
                                                  float* __restrict__ cf_out) {
    __shared__ float As[16][64];
    __shared__ float Bs[16][64];
    __shared__ float tmp[32][33];
    const int b = blockIdx.z, y0 = blockIdx.y, y1 = blockIdx.x;
    const int tid = threadIdx.x;
    const int tx = tid & 15, ty = tid >> 4;
    const float* A  = f0f + (long long)b * 524288 + y0 * 64;
    const float* Bp = f1f + (long long)b * 524288 + y1 * 64;
    int iy0a, iy0b; float wy0; interp_coef32(y0, iy0a, iy0b, wy0);
    int iy1a, iy1b; float wy1; interp_coef32(y1, iy1a, iy1b, wy1);
    const float* Cc = cws + (long long)b * 1048576;
    for (int r = tid; r < 1024; r += 256) {
        int i = r >> 5, j = r & 31;
        const float* ra = Cc + (long long)(iy0a * 32 + i) * 1024;
        const float* rb = Cc + (long long)(iy0b * 32 + i) * 1024;
        float va = ra[iy1a * 32 + j] * (1.f - wy1) + ra[iy1b * 32 + j] * wy1;
        float vb = rb[iy1a * 32 + j] * (1.f - wy1) + rb[iy1b * 32 + j] * wy1;
        tmp[i][j] = va * (1.f - wy0) + vb * wy0;
    }
    float acc[4][4] = {{0.f}};
    const int lk = tid >> 4;
    const int lc = (tid & 15) * 4;
    for (int k0 = 0; k0 < 128; k0 += 16) {
        *(float4*)&As[lk][lc] = *(const float4*)&A[(long long)(k0 + lk) * 4096 + lc];
        *(float4*)&Bs[lk][lc] = *(const float4*)&Bp[(long long)(k0 + lk) * 4096 + lc];
        __syncthreads();
#pragma unroll
        for (int kk = 0; kk < 16; ++kk) {
            float4 a4 = *(float4*)&As[kk][ty * 4];
            float4 b4 = *(float4*)&Bs[kk][tx * 4];
            float av[4] = {a4.x, a4.y, a4.z, a4.w};
            float bv[4] = {b4.x, b4.y, b4.z, b4.w};
#pragma unroll
            for (int i = 0; i < 4; ++i)
#pragma unroll
                for (int j = 0; j < 4; ++j)
                    acc[i][j] = fmaf(av[i], bv[j], acc[i][j]);
        }
        __syncthreads();
    }
    int ix0a[4], ix0b[4]; float wx0[4];
    int ix1a[4], ix1b[4]; float wx1[4];
#pragma unroll
    for (int i = 0; i < 4; ++i) interp_coef32(ty * 4 + i, ix0a[i], ix0b[i], wx0[i]);
#pragma unroll
    for (int j = 0; j < 4; ++j) interp_coef32(tx * 4 + j, ix1a[j], ix1b[j], wx1[j]);
    float val[4][4];
#pragma unroll
    for (int i = 0; i < 4; ++i)
#pragma unroll
        for (int j = 0; j < 4; ++j) {
            float ta = tmp[ix0a[i]][ix1a[j]] * (1.f - wx1[j]) + tmp[ix0a[i]][ix1b[j]] * wx1[j];
            float tb = tmp[ix0b[i]][ix1a[j]] * (1.f - wx1[j]) + tmp[ix0b[i]][ix1b[j]] * wx1[j];
            val[i][j] = (acc[i][j] * SCALE_C + (ta * (1.f - wx0[i]) + tb * wx0[i])) * 0.5f;
        }
    const long long cbase = ((long long)b << 24) + (long long)(y0 * 64) * 4096 + y1 * 64;
#pragma unroll
    for (int i = 0; i < 4; ++i)
        *(float4*)&c_out[cbase + (long long)(ty * 4 + i) * 4096 + tx * 4] =
            make_float4(val[i][0], val[i][1], val[i][2], val[i][3]);
    const long long fbase = ((long long)b << 24) + (long long)(y1 * 64) * 4096 + y0 * 64;
#pragma unroll
    for (int j = 0; j < 4; ++j)
        *(float4*)&cf_out[fbase + (long long)(tx * 4 + j) * 4096 + ty * 4] =
            make_float4(val[0][j], val[1][j], val[2][j], val[3][j]);
}

__global__ __launch_bounds__(256) void k_softargmax(const float* __restrict__ cmat,
                                                    float* __restrict__ flow_out) {
    const int tid = threadIdx.x;
    const float4* src = (const float4*)cmat + (long long)blockIdx.x * 1024;
    float4 r0 = src[tid];
    float4 r1 = src[tid + 256];
    float4 r2 = src[tid + 512];
    float4 r3 = src[tid + 768];
    float m = fmaxf(fmaxf(fmaxf(r0.x, r0.y), fmaxf(r0.z, r0.w)),
                    fmaxf(fmaxf(r1.x, r1.y), fmaxf(r1.z, r1.w)));
    m = fmaxf(m, fmaxf(fmaxf(r2.x, r2.y), fmaxf(r2.z, r2.w)));
    m = fmaxf(m, fmaxf(fmaxf(r3.x, r3.y), fmaxf(r3.z, r3.w)));
    __shared__ float red[16];
    const int lane = tid & 63, wave = tid >> 6;
#pragma unroll
    for (int off = 32; off > 0; off >>= 1) m = fmaxf(m, __shfl_xor(m, off, 64));
    if (lane == 0) red[wave] = m;
    __syncthreads();
    m = fmaxf(fmaxf(red[0], red[1]), fmaxf(red[2], red[3]));
    float l = 0.f, sx = 0.f, sy = 0.f;
#pragma unroll
    for (int s = 0; s < 4; ++s) {
        float4 r = (s == 0) ? r0 : (s == 1) ? r1 : (s == 2) ? r2 : r3;
        int f = tid + s * 256;
        float yn = -1.f + (float)(f >> 4) * STEP63;
        float xb = (float)((f & 15) * 4);
        float e0 = __expf((r.x - m) * 50.f);
        float e1 = __expf((r.y - m) * 50.f);
        float e2 = __expf((r.z - m) * 50.f);
        float e3 = __expf((r.w - m) * 50.f);
        float es = e0 + e1 + e2 + e3;
        l += es;
        sy += es * yn;
        sx += e0 * (-1.f + xb * STEP63) + e1 * (-1.f + (xb + 1.f) * STEP63)
            + e2 * (-1.f + (xb + 2.f) * STEP63) + e3 * (-1.f + (xb + 3.f) * STEP63);
    }
#pragma unroll
    for (int off = 32; off > 0; off >>= 1) {
        l  += __shfl_xor(l, off, 64);
        sx += __shfl_xor(sx, off, 64);
        sy += __shfl_xor(sy, off, 64);
    }
    if (lane == 0) { red[4 + wave] = l; red[8 + wave] = sx; red[12 + wave] = sy; }
    __syncthreads();
    if (tid == 0) {
        float L  = red[4] + red[5] + red[6] + red[7];
        float SX = red[8] + red[9] + red[10] + red[11];
        float SY = red[12] + red[13] + red[14] + red[15];
        float mx = (SX / L + 1.f) * 31.5f;
        float my = (SY / L + 1.f) * 31.5f;
        int bi = blockIdx.x;
        int b = bi >> 12, p = bi & 4095;
        flow_out[(long long)b * 8192 + p]        = mx - (float)(p & 63);
        flow_out[(long long)b * 8192 + 4096 + p] = my - (float)(p >> 6);
    }
}

// ---------------------------------------------------------------------------
// Output layout (floats): trans_features @0 | coarse @2,097,152 | c @4,194,304
// | c_flip @37,748,736 | flow @71,303,168 | flow_flip @71,319,552
// Fast path stages bf16 hi/lo planes (8 MB) in the trans_features region;
// k_copy_trans rewrites it afterwards (stream-ordered).
// ---------------------------------------------------------------------------
extern "C" void kernel_launch(void* const* d_in, const int* in_sizes, int n_in,
                              void* d_out, int out_size, void* d_ws, size_t ws_size,
                              hipStream_t stream) {
    const float* f0c = (const float*)d_in[0];
    const float* f1c = (const float*)d_in[1];
    const float* f0f = (const float*)d_in[2];
    const float* f1f = (const float*)d_in[3];
    float* out = (float*)d_out;

    float* c_out  = out + 4194304;
    float* cf_out = out + 37748736;
    float* flow   = out + 71303168;
    float* flowf  = out + 71319552;

    if (ws_size >= (size_t)16777216) {
        float* parts = (float*)d_ws;          // 2,097,152 floats (8 MB): softmax partials
        float* cws   = parts + 2097152;       // 2,097,152 floats (8 MB): coarse corr
        unsigned short* hi = (unsigned short*)out;          // 4 planes x [4096][128] bf16
        unsigned short* lo = hi + 2097152;                  // matching lo planes
        k_split<<<dim3(64, 4, 1), 256, 0, stream>>>(f0f, f1f, hi, lo);
        k_corr_c<<<dim3(16, 16, 2), 256, 0, stream>>>(f0c, f1c, cws);
        k_fused2<<<dim3(32, 32, 2), 256, 0, stream>>>(hi, cws, c_out, cf_out, parts);
        k_flow<<<4096, 256, 0, stream>>>(parts, flow, flowf);
        k_copy_trans<<<2048, 256, 0, stream>>>(f0f, f1f, out);   // overwrites plane staging
        k_coarse<<<8192, 256, 0, stream>>>(f0c, f1c, out + 2097152);
    } else {
        float* corr_ws = out;                 // reuse trans_features region as scratch
        k_corr_c<<<dim3(16, 16, 2), 256, 0, stream>>>(f0c, f1c, corr_ws);
        k_fused_fb<<<dim3(64, 64, 2), 256, 0, stream>>>(f0f, f1f, corr_ws, c_out, cf_out);
        k_copy_trans<<<2048, 256, 0, stream>>>(f0f, f1f, out);
        k_coarse<<<8192, 256, 0, stream>>>(f0c, f1c, out + 2097152);
        k_softargmax<<<8192, 256, 0, stream>>>(c_out, flow);
        k_softargmax<<<8192, 256, 0, stream>>>(cf_out, flowf);
    }
}

// Round 2
// 424.614 us; speedup vs baseline: 1.0694x; 1.0126x over previous
//
#include <hip/hip_runtime.h>
#include <math.h>

#define SCALE_C 0.08838834764831845f  // 1/sqrt(128)
#define INV_BETA 50.0f
#define STEP63 (2.0f / 63.0f)

typedef short bf16x8 __attribute__((ext_vector_type(8)));
typedef float f32x4 __attribute__((ext_vector_type(4)));

// align_corners bilinear coefficients for 32 -> 64 (src = t*31/63)
__device__ __forceinline__ void interp_coef32(int t, int& i0, int& i1, float& w) {
    float s = (float)(t * 31) / 63.0f;
    i0 = (int)floorf(s);
    if (i0 > 31) i0 = 31;
    i1 = i0 + 1;
    if (i1 > 31) i1 = 31;
    w = s - (float)i0;
}

// ---------------------------------------------------------------------------
// corr_c: [b,1024,1024] = f0c^T f1c / sqrt(128). 64x64 tile per block.
// ---------------------------------------------------------------------------
__global__ __launch_bounds__(256) void k_corr_c(const float* __restrict__ f0c,
                                                const float* __restrict__ f1c,
                                                float* __restrict__ ws) {
    __shared__ float As[16][64];
    __shared__ float Bs[16][64];
    const int b = blockIdx.z;
    const int m0 = blockIdx.y * 64, n0 = blockIdx.x * 64;
    const float* A  = f0c + (long long)b * 131072;
    const float* Bp = f1c + (long long)b * 131072;
    const int tid = threadIdx.x;
    const int tx = tid & 15, ty = tid >> 4;
    const int lk = tid >> 4;
    const int lc = (tid & 15) * 4;
    float acc[4][4] = {{0.f}};
    for (int k0 = 0; k0 < 128; k0 += 16) {
        *(float4*)&As[lk][lc] = *(const float4*)&A[(k0 + lk) * 1024 + m0 + lc];
        *(float4*)&Bs[lk][lc] = *(const float4*)&Bp[(k0 + lk) * 1024 + n0 + lc];
        __syncthreads();
#pragma unroll
        for (int kk = 0; kk < 16; ++kk) {
            float4 a4 = *(float4*)&As[kk][ty * 4];
            float4 b4 = *(float4*)&Bs[kk][tx * 4];
            float av[4] = {a4.x, a4.y, a4.z, a4.w};
            float bv[4] = {b4.x, b4.y, b4.z, b4.w};
#pragma unroll
            for (int i = 0; i < 4; ++i)
#pragma unroll
                for (int j = 0; j < 4; ++j)
                    acc[i][j] = fmaf(av[i], bv[j], acc[i][j]);
        }
        __syncthreads();
    }
#pragma unroll
    for (int i = 0; i < 4; ++i) {
        float4 w4 = make_float4(acc[i][0] * SCALE_C, acc[i][1] * SCALE_C,
                                acc[i][2] * SCALE_C, acc[i][3] * SCALE_C);
        *(float4*)&ws[(long long)b * 1048576 + (long long)(m0 + ty * 4 + i) * 1024 + n0 + tx * 4] = w4;
    }
}

// ---------------------------------------------------------------------------
// k_split: fp32 [mat][128 k][4096 pix] -> bf16 hi/lo planes [mat][pix][128 k].
// hi = RNE bf16 of x, lo = RNE bf16 of (x - hi). Planes staged in out buffer
// (trans_features region, rewritten later by k_copy_trans).
// ---------------------------------------------------------------------------
__global__ __launch_bounds__(256) void k_split(const float* __restrict__ f0f,
                                               const float* __restrict__ f1f,
                                               unsigned short* __restrict__ hi,
                                               unsigned short* __restrict__ lo) {
    __shared__ unsigned int t[64 * 132];   // packed (hi | lo<<16), [pix][k] stride 132
    const int m = blockIdx.y;              // plane: 0,1 = f0f b0,b1; 2,3 = f1f b0,b1
    const int pt = blockIdx.x;             // pixel tile (64 pix)
    const float* src = ((m >> 1) ? f1f : f0f) + (size_t)(m & 1) * 524288 + pt * 64;
    const int tid = threadIdx.x;
#pragma unroll
    for (int p = 0; p < 8; ++p) {
        int k = p * 16 + (tid >> 4);
        int px = (tid & 15) * 4;
        float4 v = *(const float4*)&src[(size_t)k * 4096 + px];
        float vv[4] = {v.x, v.y, v.z, v.w};
#pragma unroll
        for (int j = 0; j < 4; ++j) {
            float x = vv[j];
            unsigned int u = __float_as_uint(x);
            unsigned int h = (u + 0x7FFFu + ((u >> 16) & 1u)) >> 16;     // RNE bf16
            float r = x - __uint_as_float(h << 16);                      // exact
            unsigned int ur = __float_as_uint(r);
            unsigned int l2 = (ur + 0x7FFFu + ((ur >> 16) & 1u)) >> 16;  // RNE bf16
            t[(px + j) * 132 + k] = h | (l2 << 16);
        }
    }
    __syncthreads();
    const int row = tid >> 2, ks = (tid & 3) * 32;
    size_t obase = ((size_t)m * 4096 + (size_t)pt * 64 + row) * 128 + ks;
#pragma unroll
    for (int c = 0; c < 4; ++c) {
        unsigned int u[8];
        *(uint4*)&u[0] = *(const uint4*)&t[row * 132 + ks + c * 8];
        *(uint4*)&u[4] = *(const uint4*)&t[row * 132 + ks + c * 8 + 4];
        uint4 ho, lw;
        ho.x = (u[0] & 0xFFFFu) | (u[1] << 16);
        ho.y = (u[2] & 0xFFFFu) | (u[3] << 16);
        ho.z = (u[4] & 0xFFFFu) | (u[5] << 16);
        ho.w = (u[6] & 0xFFFFu) | (u[7] << 16);
        lw.x = (u[0] >> 16) | (u[1] & 0xFFFF0000u);
        lw.y = (u[2] >> 16) | (u[3] & 0xFFFF0000u);
        lw.z = (u[4] >> 16) | (u[5] & 0xFFFF0000u);
        lw.w = (u[6] >> 16) | (u[7] & 0xFFFF0000u);
        *(uint4*)&hi[obase + c * 8] = ho;
        *(uint4*)&lo[obase + c * 8] = lw;
    }
}

// ---------------------------------------------------------------------------
// k_fused2 (MFMA version): 128x128 tile of the 4096x4096 GEMM (K=128) via
// split-bf16 3-pass mfma_f32_16x16x32_bf16. 4 waves, each owns a 64x64
// sub-tile (wr=wv>>1 row-half, wc=wv&1 col-half) as 4x4 fragments of 16x16.
// Fragments load straight from the pre-transposed hi/lo planes (no LDS
// staging). C/D fragment layout: col = lane&15, row = (lane>>4)*4 + reg.
// c_out stores are vectorized via a 2-round LDS transpose (smem reused after
// the t2-based combine). parts layout unchanged (k_flow untouched).
// ---------------------------------------------------------------------------
__global__ __launch_bounds__(256, 3) void k_fused2(const unsigned short* __restrict__ planes,
                                                   const float* __restrict__ cws,
                                                   float* __restrict__ c_out,
                                                   float* __restrict__ cf_out,
                                                   float* __restrict__ parts) {
    __shared__ __attribute__((aligned(16))) float smem[8448];   // t2[4][64][33] | 64x132 stage | pred4
    const int b = blockIdx.z, by = blockIdx.y, bx = blockIdx.x;
    const int tid = threadIdx.x;
    const int wv = tid >> 6, lane = tid & 63;
    const int lr = lane & 15, lq = lane >> 4;
    const int wr = wv >> 1, wc = wv & 1;

    // ---- build t2: y0/y1/x1-interpolated coarse corr, xc0 left coarse ----
    {
        const float* Cc = cws + (size_t)b * 1048576;
        for (int e = tid; e < 8192; e += 256) {
            int pair = e >> 11, rem = e & 2047;
            int xc0 = rem >> 6, x1 = rem & 63;
            int s0 = pair >> 1, s1 = pair & 1;
            int ya, yb; float wy0; interp_coef32(2 * by + s0, ya, yb, wy0);
            int za, zb; float wy1; interp_coef32(2 * bx + s1, za, zb, wy1);
            int xa, xb; float wx1; interp_coef32(x1, xa, xb, wx1);
            const float* r0 = Cc + (size_t)(ya * 32 + xc0) * 1024;
            const float* r1 = Cc + (size_t)(yb * 32 + xc0) * 1024;
            float g0 = (r0[za * 32 + xa] * (1.f - wy1) + r0[zb * 32 + xa] * wy1) * (1.f - wy0)
                     + (r1[za * 32 + xa] * (1.f - wy1) + r1[zb * 32 + xa] * wy1) * wy0;
            float g1 = (r0[za * 32 + xb] * (1.f - wy1) + r0[zb * 32 + xb] * wy1) * (1.f - wy0)
                     + (r1[za * 32 + xb] * (1.f - wy1) + r1[zb * 32 + xb] * wy1) * wy0;
            smem[(pair * 64 + x1) * 33 + xc0] = g0 * (1.f - wx1) + g1 * wx1;
        }
    }

    // ---- split-bf16 MFMA GEMM (no LDS involved) ----
    const unsigned short* Ah = planes + (size_t)b * 524288       + (size_t)(by * 128 + wr * 64) * 128;
    const unsigned short* Bh = planes + (size_t)(2 + b) * 524288 + (size_t)(bx * 128 + wc * 64) * 128;
    f32x4 acc[4][4];
#pragma unroll
    for (int i = 0; i < 4; ++i)
#pragma unroll
        for (int j = 0; j < 4; ++j) acc[i][j] = (f32x4){0.f, 0.f, 0.f, 0.f};

#pragma unroll 2
    for (int kc = 0; kc < 4; ++kc) {
        const int ko = kc * 32 + lq * 8;
        bf16x8 ah[4], al[4], bh[4], bl[4];
#pragma unroll
        for (int t = 0; t < 4; ++t) {
            const unsigned short* pa = Ah + (size_t)(t * 16 + lr) * 128 + ko;
            const unsigned short* pb = Bh + (size_t)(t * 16 + lr) * 128 + ko;
            ah[t] = *(const bf16x8*)pa;
            al[t] = *(const bf16x8*)(pa + 2097152);   // lo planes follow hi planes
            bh[t] = *(const bf16x8*)pb;
            bl[t] = *(const bf16x8*)(pb + 2097152);
        }
#pragma unroll
        for (int ni = 0; ni < 4; ++ni)
#pragma unroll
            for (int mi = 0; mi < 4; ++mi) {
                f32x4 a = acc[mi][ni];
                a = __builtin_amdgcn_mfma_f32_16x16x32_bf16(ah[mi], bh[ni], a, 0, 0, 0);
                a = __builtin_amdgcn_mfma_f32_16x16x32_bf16(al[mi], bh[ni], a, 0, 0, 0);
                a = __builtin_amdgcn_mfma_f32_16x16x32_bf16(ah[mi], bl[ni], a, 0, 0, 0);
                acc[mi][ni] = a;
            }
    }

    __syncthreads();   // t2 fully built before any epilogue read

    // ---- epilogue: x0-interp of coarse + combine ----
#pragma unroll
    for (int mi = 0; mi < 4; ++mi)
#pragma unroll
        for (int dr = 0; dr < 4; ++dr) {
            int x0 = mi * 16 + lq * 4 + dr;
            float s = (float)(x0 * 31) / 63.0f;
            int i0 = (int)s;
            float w = s - (float)i0;
            int i1 = i0 + 1; if (i1 > 31) i1 = 31;
#pragma unroll
            for (int ni = 0; ni < 4; ++ni) {
                const float* t2 = &smem[(wv * 64 + ni * 16 + lr) * 33];
                float up = t2[i0] * (1.f - w) + t2[i1] * w;
                acc[mi][ni][dr] = (acc[mi][ni][dr] * SCALE_C + up) * 0.5f;
            }
        }

    // ---- c_flip stores: float4, dr contiguous (no LDS needed) ----
    const int rowbase = by * 128 + wr * 64, colbase = bx * 128 + wc * 64;
    {
        size_t fb = ((size_t)b << 24) + (size_t)colbase * 4096 + rowbase;
#pragma unroll
        for (int mi = 0; mi < 4; ++mi)
#pragma unroll
            for (int ni = 0; ni < 4; ++ni) {
                int co = ni * 16 + lr;
                *(float4*)&cf_out[fb + (size_t)co * 4096 + mi * 16 + lq * 4] =
                    make_float4(acc[mi][ni][0], acc[mi][ni][1], acc[mi][ni][2], acc[mi][ni][3]);
            }
    }

    // ---- c stores: 2-round LDS transpose -> coalesced float4 rows ----
    // Stage: rows r*64..r*64+63 of the block tile, stride 132, XOR-swizzled
    // column-quad (c4 ^= (row&7)<<2) to spread banks.
#pragma unroll
    for (int r = 0; r < 2; ++r) {
        __syncthreads();   // t2 reads (r=0) / previous-round reads (r=1) done
        if (wr == r) {
#pragma unroll
            for (int mi = 0; mi < 4; ++mi)
#pragma unroll
                for (int dr = 0; dr < 4; ++dr) {
                    int rl = mi * 16 + lq * 4 + dr;
                    int sw = (rl & 7) << 2;
#pragma unroll
                    for (int ni = 0; ni < 4; ++ni) {
                        int col = wc * 64 + ni * 16 + lr;
                        int c4 = col >> 2;
                        smem[rl * 132 + ((c4 ^ sw) << 2) + (col & 3)] = acc[mi][ni][dr];
                    }
                }
        }
        __syncthreads();
        size_t cb = ((size_t)b << 24) + (size_t)(by * 128 + r * 64) * 4096 + bx * 128;
#pragma unroll
        for (int i = 0; i < 8; ++i) {
            int f = tid + i * 256;          // [0,2048)
            int rl = f >> 5, c4 = f & 31;
            float4 v = *(float4*)&smem[rl * 132 + ((c4 ^ ((rl & 7) << 2)) << 2)];
            *(float4*)&c_out[cb + (size_t)rl * 4096 + c4 * 4] = v;
        }
    }

    // ---- softmax partials ----
    float4* pred4 = (float4*)smem;
    float4* parts4 = (float4*)parts;
    __syncthreads();   // transpose reads done; reuse LDS as pred4

    // c-direction: per row, reduce over this wave's 64 cols (lanes sharing lq)
    {
        float yn1 = -1.f + (float)(2 * bx + wc) * STEP63;
#pragma unroll
        for (int mi = 0; mi < 4; ++mi)
#pragma unroll
            for (int dr = 0; dr < 4; ++dr) {
                float m = fmaxf(fmaxf(acc[mi][0][dr], acc[mi][1][dr]),
                                fmaxf(acc[mi][2][dr], acc[mi][3][dr]));
                m = fmaxf(m, __shfl_xor(m, 1, 64));
                m = fmaxf(m, __shfl_xor(m, 2, 64));
                m = fmaxf(m, __shfl_xor(m, 4, 64));
                m = fmaxf(m, __shfl_xor(m, 8, 64));
                float l = 0.f, sx = 0.f;
#pragma unroll
                for (int ni = 0; ni < 4; ++ni) {
                    float e = __expf((acc[mi][ni][dr] - m) * INV_BETA);
                    l += e;
                    sx += e * (-1.f + (float)(ni * 16 + lr) * STEP63);
                }
                l += __shfl_xor(l, 1, 64);  sx += __shfl_xor(sx, 1, 64);
                l += __shfl_xor(l, 2, 64);  sx += __shfl_xor(sx, 2, 64);
                l += __shfl_xor(l, 4, 64);  sx += __shfl_xor(sx, 4, 64);
                l += __shfl_xor(l, 8, 64);  sx += __shfl_xor(sx, 8, 64);
                if (lr == 0)
                    pred4[wc * 128 + wr * 64 + mi * 16 + lq * 4 + dr] = make_float4(m, l, sx, yn1 * l);
            }
    }
    __syncthreads();
    if (tid < 128) {
        float4 h0 = pred4[tid], h1 = pred4[128 + tid];
        float M = fmaxf(h0.x, h1.x);
        float s0 = __expf((h0.x - M) * INV_BETA);
        float s1 = __expf((h1.x - M) * INV_BETA);
        parts4[((size_t)b * 4096 + by * 128 + tid) * 32 + bx] =
            make_float4(M, h0.y * s0 + h1.y * s1, h0.z * s0 + h1.z * s1, h0.w * s0 + h1.w * s1);
    }
    __syncthreads();

    // f-direction: per col, reduce over this wave's 64 rows (lanes sharing lr)
    {
        float yn0 = -1.f + (float)(2 * by + wr) * STEP63;
#pragma unroll
        for (int ni = 0; ni < 4; ++ni) {
            float m = acc[0][ni][0];
#pragma unroll
            for (int mi = 0; mi < 4; ++mi)
#pragma unroll
                for (int dr = 0; dr < 4; ++dr) m = fmaxf(m, acc[mi][ni][dr]);
            m = fmaxf(m, __shfl_xor(m, 16, 64));
            m = fmaxf(m, __shfl_xor(m, 32, 64));
            float l = 0.f, sx = 0.f;
#pragma unroll
            for (int mi = 0; mi < 4; ++mi)
#pragma unroll
                for (int dr = 0; dr < 4; ++dr) {
                    float e = __expf((acc[mi][ni][dr] - m) * INV_BETA);
                    l += e;
                    sx += e * (-1.f + (float)(mi * 16 + lq * 4 + dr) * STEP63);
                }
            l += __shfl_xor(l, 16, 64);  sx += __shfl_xor(sx, 16, 64);
            l += __shfl_xor(l, 32, 64);  sx += __shfl_xor(sx, 32, 64);
            if (lq == 0)
                pred4[wr * 128 + wc * 64 + ni * 16 + lr] = make_float4(m, l, sx, yn0 * l);
        }
    }
    __syncthreads();
    if (tid < 128) {
        float4 h0 = pred4[tid], h1 = pred4[128 + tid];
        float M = fmaxf(h0.x, h1.x);
        float s0 = __expf((h0.x - M) * INV_BETA);
        float s1 = __expf((h1.x - M) * INV_BETA);
        parts4[262144 + ((size_t)b * 4096 + bx * 128 + tid) * 32 + by] =
            make_float4(M, h0.y * s0 + h1.y * s1, h0.z * s0 + h1.z * s1, h0.w * s0 + h1.w * s1);
    }
}

// ---------------------------------------------------------------------------
// k_flow: merge 32 partials per row -> flow values. One wave per row.
// ---------------------------------------------------------------------------
__global__ __launch_bounds__(256) void k_flow(const float* __restrict__ parts,
                                              float* __restrict__ flow,
                                              float* __restrict__ flowf) {
    const int row = blockIdx.x * 4 + (threadIdx.x >> 6);
    const int lane = threadIdx.x & 63;
    const float4* p4 = (const float4*)parts + (long long)row * 32;
    float m = -1e30f, l = 0.f, sx = 0.f, sy = 0.f;
    if (lane < 32) { float4 v = p4[lane]; m = v.x; l = v.y; sx = v.z; sy = v.w; }
    float M = m;
#pragma unroll
    for (int off = 1; off < 64; off <<= 1) M = fmaxf(M, __shfl_xor(M, off, 64));
    float s = __expf((m - M) * INV_BETA);
    l *= s; sx *= s; sy *= s;
#pragma unroll
    for (int off = 1; off < 64; off <<= 1) {
        l += __shfl_xor(l, off, 64);
        sx += __shfl_xor(sx, off, 64);
        sy += __shfl_xor(sy, off, 64);
    }
    if (lane == 0) {
        float gx = sx / l, gy = sy / l;
        float mx = (gx + 1.f) * 31.5f, my = (gy + 1.f) * 31.5f;
        int dir = row >> 13, b = (row >> 12) & 1, p = row & 4095;
        float* o = dir ? flowf : flow;
        o[(long long)b * 8192 + p] = mx - (float)(p & 63);
        o[(long long)b * 8192 + 4096 + p] = my - (float)(p >> 6);
    }
}

// ---------------------------------------------------------------------------
// trans_features = stack([f0f, f1f], axis=1)
// ---------------------------------------------------------------------------
__global__ void k_copy_trans(const float* __restrict__ f0f, const float* __restrict__ f1f,
                             float* __restrict__ out1) {
    int idx = blockIdx.x * 256 + threadIdx.x;
    int bv = idx >> 17;
    int r = idx & 131071;
    int b = bv >> 1, v = bv & 1;
    const float4* src = (const float4*)(v ? f1f : f0f) + (long long)b * 131072 + r;
    ((float4*)out1)[idx] = *src;
}

// ---------------------------------------------------------------------------
// trans_features_coarse: bilinear 32->64 of stacked feat_c
// ---------------------------------------------------------------------------
__global__ void k_coarse(const float* __restrict__ f0c, const float* __restrict__ f1c,
                         float* __restrict__ out2) {
    int idx = blockIdx.x * 256 + threadIdx.x;
    int x = idx & 63, y = (idx >> 6) & 63, ch = (idx >> 12) & 127;
    int v = (idx >> 19) & 1, b = idx >> 20;
    int iy0, iy1; float wy; interp_coef32(y, iy0, iy1, wy);
    int ix0, ix1; float wx; interp_coef32(x, ix0, ix1, wx);
    const float* src = (v ? f1c : f0c) + (long long)(b * 128 + ch) * 1024;
    float a  = src[iy0 * 32 + ix0] * (1.f - wy) + src[iy1 * 32 + ix0] * wy;
    float c2 = src[iy0 * 32 + ix1] * (1.f - wy) + src[iy1 * 32 + ix1] * wy;
    out2[idx] = a * (1.f - wx) + c2 * wx;
}

// ========================= fallback path (round-1) =========================
__global__ __launch_bounds__(256) void k_fused_fb(const float* __restrict__ f0f,
                                                  const float* __restrict__ f1f,
                                                  const float* __restrict__ cws,
                                                  float* __restrict__ c_out,
                                                  float* __restrict__ cf_out) {
    __shared__ float As[16][64];
    __shared__ float Bs[16][64];
    __shared__ float tmp[32][33];
    const int b = blockIdx.z, y0 = blockIdx.y, y1 = blockIdx.x;
    const int tid = threadIdx.x;
    const int tx = tid & 15, ty = tid >> 4;
    const float* A  = f0f + (long long)b * 524288 + y0 * 64;
    const float* Bp = f1f + (long long)b * 524288 + y1 * 64;
    int iy0a, iy0b; float wy0; interp_coef32(y0, iy0a, iy0b, wy0);
    int iy1a, iy1b; float wy1; interp_coef32(y1, iy1a, iy1b, wy1);
    const float* Cc = cws + (long long)b * 1048576;
    for (int r = tid; r < 1024; r += 256) {
        int i = r >> 5, j = r & 31;
        const float* ra = Cc + (long long)(iy0a * 32 + i) * 1024;
        const float* rb = Cc + (long long)(iy0b * 32 + i) * 1024;
        float va = ra[iy1a * 32 + j] * (1.f - wy1) + ra[iy1b * 32 + j] * wy1;
        float vb = rb[iy1a * 32 + j] * (1.f - wy1) + rb[iy1b * 32 + j] * wy1;
        tmp[i][j] = va * (1.f - wy0) + vb * wy0;
    }
    float acc[4][4] = {{0.f}};
    const int lk = tid >> 4;
    const int lc = (tid & 15) * 4;
    for (int k0 = 0; k0 < 128; k0 += 16) {
        *(float4*)&As[lk][lc] = *(const float4*)&A[(long long)(k0 + lk) * 4096 + lc];
        *(float4*)&Bs[lk][lc] = *(const float4*)&Bp[(long long)(k0 + lk) * 4096 + lc];
        __syncthreads();
#pragma unroll
        for (int kk = 0; kk < 16; ++kk) {
            float4 a4 = *(float4*)&As[kk][ty * 4];
            float4 b4 = *(float4*)&Bs[kk][tx * 4];
            float av[4] = {a4.x, a4.y, a4.z, a4.w};
            float bv[4] = {b4.x, b4.y, b4.z, b4.w};
#pragma unroll
            for (int i = 0; i < 4; ++i)
#pragma unroll
                for (int j = 0; j < 4; ++j)
                    acc[i][j] = fmaf(av[i], bv[j], acc[i][j]);
        }
        __syncthreads();
    }
    int ix0a[4], ix0b[4]; float wx0[4];
    int ix1a[4], ix1b[4]; float wx1[4];
#pragma unroll
    for (int i = 0; i < 4; ++i) interp_coef32(ty * 4 + i, ix0a[i], ix0b[i], wx0[i]);
#pragma unroll
    for (int j = 0; j < 4; ++j) interp_coef32(tx * 4 + j, ix1a[j], ix1b[j], wx1[j]);
    float val[4][4];
#pragma unroll
    for (int i = 0; i < 4; ++i)
#pragma unroll
        for (int j = 0; j < 4; ++j) {
            float ta = tmp[ix0a[i]][ix1a[j]] * (1.f - wx1[j]) + tmp[ix0a[i]][ix1b[j]] * wx1[j];
            float tb = tmp[ix0b[i]][ix1a[j]] * (1.f - wx1[j]) + tmp[ix0b[i]][ix1b[j]] * wx1[j];
            val[i][j] = (acc[i][j] * SCALE_C + (ta * (1.f - wx0[i]) + tb * wx0[i])) * 0.5f;
        }
    const long long cbase = ((long long)b << 24) + (long long)(y0 * 64) * 4096 + y1 * 64;
#pragma unroll
    for (int i = 0; i < 4; ++i)
        *(float4*)&c_out[cbase + (long long)(ty * 4 + i) * 4096 + tx * 4] =
            make_float4(val[i][0], val[i][1], val[i][2], val[i][3]);
    const long long fbase = ((long long)b << 24) + (long long)(y1 * 64) * 4096 + y0 * 64;
#pragma unroll
    for (int j = 0; j < 4; ++j)
        *(float4*)&cf_out[fbase + (long long)(tx * 4 + j) * 4096 + ty * 4] =
            make_float4(val[0][j], val[1][j], val[2][j], val[3][j]);
}

__global__ __launch_bounds__(256) void k_softargmax(const float* __restrict__ cmat,
                                                    float* __restrict__ flow_out) {
    const int tid = threadIdx.x;
    const float4* src = (const float4*)cmat + (long long)blockIdx.x * 1024;
    float4 r0 = src[tid];
    float4 r1 = src[tid + 256];
    float4 r2 = src[tid + 512];
    float4 r3 = src[tid + 768];
    float m = fmaxf(fmaxf(fmaxf(r0.x, r0.y), fmaxf(r0.z, r0.w)),
                    fmaxf(fmaxf(r1.x, r1.y), fmaxf(r1.z, r1.w)));
    m = fmaxf(m, fmaxf(fmaxf(r2.x, r2.y), fmaxf(r2.z, r2.w)));
    m = fmaxf(m, fmaxf(fmaxf(r3.x, r3.y), fmaxf(r3.z, r3.w)));
    __shared__ float red[16];
    const int lane = tid & 63, wave = tid >> 6;
#pragma unroll
    for (int off = 32; off > 0; off >>= 1) m = fmaxf(m, __shfl_xor(m, off, 64));
    if (lane == 0) red[wave] = m;
    __syncthreads();
    m = fmaxf(fmaxf(red[0], red[1]), fmaxf(red[2], red[3]));
    float l = 0.f, sx = 0.f, sy = 0.f;
#pragma unroll
    for (int s = 0; s < 4; ++s) {
        float4 r = (s == 0) ? r0 : (s == 1) ? r1 : (s == 2) ? r2 : r3;
        int f = tid + s * 256;
        float yn = -1.f + (float)(f >> 4) * STEP63;
        float xb = (float)((f & 15) * 4);
        float e0 = __expf((r.x - m) * 50.f);
        float e1 = __expf((r.y - m) * 50.f);
        float e2 = __expf((r.z - m) * 50.f);
        float e3 = __expf((r.w - m) * 50.f);
        float es = e0 + e1 + e2 + e3;
        l += es;
        sy += es * yn;
        sx += e0 * (-1.f + xb * STEP63) + e1 * (-1.f + (xb + 1.f) * STEP63)
            + e2 * (-1.f + (xb + 2.f) * STEP63) + e3 * (-1.f + (xb + 3.f) * STEP63);
    }
#pragma unroll
    for (int off = 32; off > 0; off >>= 1) {
        l  += __shfl_xor(l, off, 64);
        sx += __shfl_xor(sx, off, 64);
        sy += __shfl_xor(sy, off, 64);
    }
    if (lane == 0) { red[4 + wave] = l; red[8 + wave] = sx; red[12 + wave] = sy; }
    __syncthreads();
    if (tid == 0) {
        float L  = red[4] + red[5] + red[6] + red[7];
        float SX = red[8] + red[9] + red[10] + red[11];
        float SY = red[12] + red[13] + red[14] + red[15];
        float mx = (SX / L + 1.f) * 31.5f;
        float my = (SY / L + 1.f) * 31.5f;
        int bi = blockIdx.x;
        int b = bi >> 12, p = bi & 4095;
        flow_out[(long long)b * 8192 + p]        = mx - (float)(p & 63);
        flow_out[(long long)b * 8192 + 4096 + p] = my - (float)(p >> 6);
    }
}

// ---------------------------------------------------------------------------
// Output layout (floats): trans_features @0 | coarse @2,097,152 | c @4,194,304
// | c_flip @37,748,736 | flow @71,303,168 | flow_flip @71,319,552
// Fast path stages bf16 hi/lo planes (8 MB) in the trans_features region;
// k_copy_trans rewrites it afterwards (stream-ordered).
// ---------------------------------------------------------------------------
extern "C" void kernel_launch(void* const* d_in, const int* in_sizes, int n_in,
                              void* d_out, int out_size, void* d_ws, size_t ws_size,
                              hipStream_t stream) {
    const float* f0c = (const float*)d_in[0];
    const float* f1c = (const float*)d_in[1];
    const float* f0f = (const float*)d_in[2];
    const float* f1f = (const float*)d_in[3];
    float* out = (float*)d_out;

    float* c_out  = out + 4194304;
    float* cf_out = out + 37748736;
    float* flow   = out + 71303168;
    float* flowf  = out + 71319552;

    if (ws_size >= (size_t)16777216) {
        float* parts = (float*)d_ws;          // 2,097,152 floats (8 MB): softmax partials
        float* cws   = parts + 2097152;       // 2,097,152 floats (8 MB): coarse corr
        unsigned short* hi = (unsigned short*)out;          // 4 planes x [4096][128] bf16
        unsigned short* lo = hi + 2097152;                  // matching lo planes
        k_split<<<dim3(64, 4, 1), 256, 0, stream>>>(f0f, f1f, hi, lo);
        k_corr_c<<<dim3(16, 16, 2), 256, 0, stream>>>(f0c, f1c, cws);
        k_fused2<<<dim3(32, 32, 2), 256, 0, stream>>>(hi, cws, c_out, cf_out, parts);
        k_flow<<<4096, 256, 0, stream>>>(parts, flow, flowf);
        k_copy_trans<<<2048, 256, 0, stream>>>(f0f, f1f, out);   // overwrites plane staging
        k_coarse<<<8192, 256, 0, stream>>>(f0c, f1c, out + 2097152);
    } else {
        float* corr_ws = out;                 // reuse trans_features region as scratch
        k_corr_c<<<dim3(16, 16, 2), 256, 0, stream>>>(f0c, f1c, corr_ws);
        k_fused_fb<<<dim3(64, 64, 2), 256, 0, stream>>>(f0f, f1f, corr_ws, c_out, cf_out);
        k_copy_trans<<<2048, 256, 0, stream>>>(f0f, f1f, out);
        k_coarse<<<8192, 256, 0, stream>>>(f0c, f1c, out + 2097152);
        k_softargmax<<<8192, 256, 0, stream>>>(c_out, flow);
        k_softargmax<<<8192, 256, 0, stream>>>(cf_out, flowf);
    }
}

// Round 3
// 408.285 us; speedup vs baseline: 1.1122x; 1.0400x over previous
//
#include <hip/hip_runtime.h>
#include <math.h>

#define SCALE_C 0.08838834764831845f  // 1/sqrt(128)
#define INV_BETA 50.0f
#define STEP63 (2.0f / 63.0f)

typedef short bf16x8 __attribute__((ext_vector_type(8)));
typedef float f32x4 __attribute__((ext_vector_type(4)));

// align_corners bilinear coefficients for 32 -> 64 (src = t*31/63)
__device__ __forceinline__ void interp_coef32(int t, int& i0, int& i1, float& w) {
    float s = (float)(t * 31) / 63.0f;
    i0 = (int)floorf(s);
    if (i0 > 31) i0 = 31;
    i1 = i0 + 1;
    if (i1 > 31) i1 = 31;
    w = s - (float)i0;
}

// ---------------------------------------------------------------------------
// corr_c: [b,1024,1024] = f0c^T f1c / sqrt(128). 64x64 tile per block.
// ---------------------------------------------------------------------------
__global__ __launch_bounds__(256) void k_corr_c(const float* __restrict__ f0c,
                                                const float* __restrict__ f1c,
                                                float* __restrict__ ws) {
    __shared__ float As[16][64];
    __shared__ float Bs[16][64];
    const int b = blockIdx.z;
    const int m0 = blockIdx.y * 64, n0 = blockIdx.x * 64;
    const float* A  = f0c + (long long)b * 131072;
    const float* Bp = f1c + (long long)b * 131072;
    const int tid = threadIdx.x;
    const int tx = tid & 15, ty = tid >> 4;
    const int lk = tid >> 4;
    const int lc = (tid & 15) * 4;
    float acc[4][4] = {{0.f}};
    for (int k0 = 0; k0 < 128; k0 += 16) {
        *(float4*)&As[lk][lc] = *(const float4*)&A[(k0 + lk) * 1024 + m0 + lc];
        *(float4*)&Bs[lk][lc] = *(const float4*)&Bp[(k0 + lk) * 1024 + n0 + lc];
        __syncthreads();
#pragma unroll
        for (int kk = 0; kk < 16; ++kk) {
            float4 a4 = *(float4*)&As[kk][ty * 4];
            float4 b4 = *(float4*)&Bs[kk][tx * 4];
            float av[4] = {a4.x, a4.y, a4.z, a4.w};
            float bv[4] = {b4.x, b4.y, b4.z, b4.w};
#pragma unroll
            for (int i = 0; i < 4; ++i)
#pragma unroll
                for (int j = 0; j < 4; ++j)
                    acc[i][j] = fmaf(av[i], bv[j], acc[i][j]);
        }
        __syncthreads();
    }
#pragma unroll
    for (int i = 0; i < 4; ++i) {
        float4 w4 = make_float4(acc[i][0] * SCALE_C, acc[i][1] * SCALE_C,
                                acc[i][2] * SCALE_C, acc[i][3] * SCALE_C);
        *(float4*)&ws[(long long)b * 1048576 + (long long)(m0 + ty * 4 + i) * 1024 + n0 + tx * 4] = w4;
    }
}

// ---------------------------------------------------------------------------
// k_split: fp32 [mat][128 k][4096 pix] -> bf16 hi/lo planes [mat][pix][128 k].
// ---------------------------------------------------------------------------
__global__ __launch_bounds__(256) void k_split(const float* __restrict__ f0f,
                                               const float* __restrict__ f1f,
                                               unsigned short* __restrict__ hi,
                                               unsigned short* __restrict__ lo) {
    __shared__ unsigned int t[64 * 132];   // packed (hi | lo<<16), [pix][k] stride 132
    const int m = blockIdx.y;              // plane: 0,1 = f0f b0,b1; 2,3 = f1f b0,b1
    const int pt = blockIdx.x;             // pixel tile (64 pix)
    const float* src = ((m >> 1) ? f1f : f0f) + (size_t)(m & 1) * 524288 + pt * 64;
    const int tid = threadIdx.x;
#pragma unroll
    for (int p = 0; p < 8; ++p) {
        int k = p * 16 + (tid >> 4);
        int px = (tid & 15) * 4;
        float4 v = *(const float4*)&src[(size_t)k * 4096 + px];
        float vv[4] = {v.x, v.y, v.z, v.w};
#pragma unroll
        for (int j = 0; j < 4; ++j) {
            float x = vv[j];
            unsigned int u = __float_as_uint(x);
            unsigned int h = (u + 0x7FFFu + ((u >> 16) & 1u)) >> 16;     // RNE bf16
            float r = x - __uint_as_float(h << 16);                      // exact
            unsigned int ur = __float_as_uint(r);
            unsigned int l2 = (ur + 0x7FFFu + ((ur >> 16) & 1u)) >> 16;  // RNE bf16
            t[(px + j) * 132 + k] = h | (l2 << 16);
        }
    }
    __syncthreads();
    const int row = tid >> 2, ks = (tid & 3) * 32;
    size_t obase = ((size_t)m * 4096 + (size_t)pt * 64 + row) * 128 + ks;
#pragma unroll
    for (int c = 0; c < 4; ++c) {
        unsigned int u[8];
        *(uint4*)&u[0] = *(const uint4*)&t[row * 132 + ks + c * 8];
        *(uint4*)&u[4] = *(const uint4*)&t[row * 132 + ks + c * 8 + 4];
        uint4 ho, lw;
        ho.x = (u[0] & 0xFFFFu) | (u[1] << 16);
        ho.y = (u[2] & 0xFFFFu) | (u[3] << 16);
        ho.z = (u[4] & 0xFFFFu) | (u[5] << 16);
        ho.w = (u[6] & 0xFFFFu) | (u[7] << 16);
        lw.x = (u[0] >> 16) | (u[1] & 0xFFFF0000u);
        lw.y = (u[2] >> 16) | (u[3] & 0xFFFF0000u);
        lw.z = (u[4] >> 16) | (u[5] & 0xFFFF0000u);
        lw.w = (u[6] >> 16) | (u[7] & 0xFFFF0000u);
        *(uint4*)&hi[obase + c * 8] = ho;
        *(uint4*)&lo[obase + c * 8] = lw;
    }
}

// ---------------------------------------------------------------------------
// k_fused2: 128x128 tile of the 4096x4096 GEMM (K=128) via split-bf16 3-pass
// mfma_f32_16x16x32_bf16. 4 waves, each owns a 64x64 sub-tile.
// t2 is built SEPARABLY in LDS (SA coarse sub-block -> F y-interp -> t2
// x1-interp; bit-identical op tree to the direct gather).
// BOTH c and c_flip stores go through 2-round swizzled LDS transposes so all
// global stores are 512B-contiguous per 32 lanes (kills the 16KB-stride
// per-lane scatter that made cf_out transaction-bound).
// LDS: region0 [0,9216) = SA -> t2 -> store-stage -> pred4; region1
// [9216,13440) = F. 53.8 KB -> 3 blocks/CU.
// ---------------------------------------------------------------------------
__global__ __launch_bounds__(256, 3) void k_fused2(const unsigned short* __restrict__ planes,
                                                   const float* __restrict__ cws,
                                                   float* __restrict__ c_out,
                                                   float* __restrict__ cf_out,
                                                   float* __restrict__ parts) {
    __shared__ __attribute__((aligned(16))) float smem[13440];
    float* const Freg = smem + 9216;        // F[4][32][33]
    const int b = blockIdx.z, by = blockIdx.y, bx = blockIdx.x;
    const int tid = threadIdx.x;
    const int wv = tid >> 6, lane = tid & 63;
    const int lr = lane & 15, lq = lane >> 4;
    const int wr = wv >> 1, wc = wv & 1;

    const int y0base = (2 * by * 31) / 63;
    const int y1base = (2 * bx * 31) / 63;

    // ---- stage A: coarse sub-block SA[dy0][x0c][dy1][x1c] (linear = e) ----
    {
        const float* Cc = cws + (size_t)b * 1048576;
        for (int e = tid; e < 9216; e += 256) {
            int x1c = e & 31;
            int q = e >> 5;                         // 0..287
            int r = (q * 21846) >> 16;              // q/3
            int dy1 = q - r * 3;
            int x0c = r & 31;
            int dy0 = r >> 5;
            int y0r = y0base + dy0; if (y0r > 31) y0r = 31;
            int y1r = y1base + dy1; if (y1r > 31) y1r = 31;
            smem[e] = Cc[(size_t)(y0r * 32 + x0c) * 1024 + y1r * 32 + x1c];
        }
    }
    __syncthreads();

    // ---- stage B: F[p][x0c][x1c] = y0,y1 interp from SA ----
    {
        for (int e = tid; e < 4096; e += 256) {
            int x1c = e & 31, x0c = (e >> 5) & 31, p = e >> 10;
            int s0 = p >> 1, s1 = p & 1;
            int ya, yb; float wy0; interp_coef32(2 * by + s0, ya, yb, wy0);
            int za, zb; float wy1; interp_coef32(2 * bx + s1, za, zb, wy1);
            int a0 = ya - y0base, a1 = yb - y0base;
            int b0 = za - y1base, b1 = zb - y1base;
            const float* s00 = &smem[((a0 * 32 + x0c) * 3) * 32 + x1c];
            const float* s10 = &smem[((a1 * 32 + x0c) * 3) * 32 + x1c];
            float g0 = s00[b0 * 32] * (1.f - wy1) + s00[b1 * 32] * wy1;
            float g1 = s10[b0 * 32] * (1.f - wy1) + s10[b1 * 32] * wy1;
            Freg[(p * 32 + x0c) * 33 + x1c] = g0 * (1.f - wy0) + g1 * wy0;
        }
    }
    __syncthreads();   // F done; SA dead (t2 overwrites region0)

    // ---- stage C: t2[p][x1][x0c] = x1 interp of F ----
    {
        for (int e = tid; e < 8192; e += 256) {
            int x1 = e & 63, x0c = (e >> 6) & 31, p = e >> 11;
            int xa, xb; float wx1; interp_coef32(x1, xa, xb, wx1);
            const float* Fp = &Freg[(p * 32 + x0c) * 33];
            smem[(p * 64 + x1) * 33 + x0c] = Fp[xa] * (1.f - wx1) + Fp[xb] * wx1;
        }
    }

    // ---- split-bf16 MFMA GEMM (no LDS involved) ----
    const unsigned short* Ah = planes + (size_t)b * 524288       + (size_t)(by * 128 + wr * 64) * 128;
    const unsigned short* Bh = planes + (size_t)(2 + b) * 524288 + (size_t)(bx * 128 + wc * 64) * 128;
    f32x4 acc[4][4];
#pragma unroll
    for (int i = 0; i < 4; ++i)
#pragma unroll
        for (int j = 0; j < 4; ++j) acc[i][j] = (f32x4){0.f, 0.f, 0.f, 0.f};

#pragma unroll 2
    for (int kc = 0; kc < 4; ++kc) {
        const int ko = kc * 32 + lq * 8;
        bf16x8 ah[4], al[4], bh[4], bl[4];
#pragma unroll
        for (int t = 0; t < 4; ++t) {
            const unsigned short* pa = Ah + (size_t)(t * 16 + lr) * 128 + ko;
            const unsigned short* pb = Bh + (size_t)(t * 16 + lr) * 128 + ko;
            ah[t] = *(const bf16x8*)pa;
            al[t] = *(const bf16x8*)(pa + 2097152);   // lo planes follow hi planes
            bh[t] = *(const bf16x8*)pb;
            bl[t] = *(const bf16x8*)(pb + 2097152);
        }
#pragma unroll
        for (int ni = 0; ni < 4; ++ni)
#pragma unroll
            for (int mi = 0; mi < 4; ++mi) {
                f32x4 a = acc[mi][ni];
                a = __builtin_amdgcn_mfma_f32_16x16x32_bf16(ah[mi], bh[ni], a, 0, 0, 0);
                a = __builtin_amdgcn_mfma_f32_16x16x32_bf16(al[mi], bh[ni], a, 0, 0, 0);
                a = __builtin_amdgcn_mfma_f32_16x16x32_bf16(ah[mi], bl[ni], a, 0, 0, 0);
                acc[mi][ni] = a;
            }
    }

    __syncthreads();   // t2 fully written before epilogue reads

    // ---- epilogue: x0-interp of coarse + combine ----
#pragma unroll
    for (int mi = 0; mi < 4; ++mi)
#pragma unroll
        for (int dr = 0; dr < 4; ++dr) {
            int x0 = mi * 16 + lq * 4 + dr;
            float s = (float)(x0 * 31) / 63.0f;
            int i0 = (int)s;
            float w = s - (float)i0;
            int i1 = i0 + 1; if (i1 > 31) i1 = 31;
#pragma unroll
            for (int ni = 0; ni < 4; ++ni) {
                const float* t2 = &smem[(wv * 64 + ni * 16 + lr) * 33];
                float up = t2[i0] * (1.f - w) + t2[i1] * w;
                acc[mi][ni][dr] = (acc[mi][ni][dr] * SCALE_C + up) * 0.5f;
            }
        }

    // ---- c stores: 2-round LDS transpose -> coalesced float4 rows ----
#pragma unroll
    for (int r = 0; r < 2; ++r) {
        __syncthreads();   // t2/previous-round reads done
        if (wr == r) {
#pragma unroll
            for (int mi = 0; mi < 4; ++mi)
#pragma unroll
                for (int dr = 0; dr < 4; ++dr) {
                    int rl = mi * 16 + lq * 4 + dr;
                    int sw = (rl & 7) << 2;
#pragma unroll
                    for (int ni = 0; ni < 4; ++ni) {
                        int col = wc * 64 + ni * 16 + lr;
                        int c4 = col >> 2;
                        smem[rl * 132 + ((c4 ^ sw) << 2) + (col & 3)] = acc[mi][ni][dr];
                    }
                }
        }
        __syncthreads();
        size_t cb = ((size_t)b << 24) + (size_t)(by * 128 + r * 64) * 4096 + bx * 128;
#pragma unroll
        for (int i = 0; i < 8; ++i) {
            int f = tid + i * 256;          // [0,2048)
            int rl = f >> 5, c4 = f & 31;
            float4 v = *(float4*)&smem[rl * 132 + ((c4 ^ ((rl & 7) << 2)) << 2)];
            *(float4*)&c_out[cb + (size_t)rl * 4096 + c4 * 4] = v;
        }
    }

    // ---- c_flip stores: 2-round LDS transpose (rows of cf = tile cols) ----
    // Stage buffer: [col 0..63][rowquad q 0..31] float4, stride 132 floats,
    // swizzled q ^= (col&7)<<2. Waves with wc==r own cols r*64..r*64+63.
#pragma unroll
    for (int r = 0; r < 2; ++r) {
        __syncthreads();   // previous-round reads done
        if (wc == r) {
#pragma unroll
            for (int ni = 0; ni < 4; ++ni) {
                int col = ni * 16 + lr;     // local col within this half
                int sw = (col & 7) << 2;
#pragma unroll
                for (int mi = 0; mi < 4; ++mi) {
                    int q = wr * 16 + mi * 4 + lq;   // row-quad in [0,32)
                    *(float4*)&smem[col * 132 + ((q ^ sw) << 2)] =
                        make_float4(acc[mi][ni][0], acc[mi][ni][1], acc[mi][ni][2], acc[mi][ni][3]);
                }
            }
        }
        __syncthreads();
        size_t fb = ((size_t)b << 24) + (size_t)(bx * 128 + r * 64) * 4096 + by * 128;
#pragma unroll
        for (int i = 0; i < 8; ++i) {
            int f = tid + i * 256;          // [0,2048)
            int col = f >> 5, q = f & 31;
            float4 v = *(float4*)&smem[col * 132 + ((q ^ ((col & 7) << 2)) << 2)];
            *(float4*)&cf_out[fb + (size_t)col * 4096 + q * 4] = v;
        }
    }

    // ---- softmax partials ----
    float4* pred4 = (float4*)smem;
    float4* parts4 = (float4*)parts;
    __syncthreads();   // transpose reads done; reuse LDS as pred4

    // c-direction: per row, reduce over this wave's 64 cols (lanes sharing lq)
    {
        float yn1 = -1.f + (float)(2 * bx + wc) * STEP63;
#pragma unroll
        for (int mi = 0; mi < 4; ++mi)
#pragma unroll
            for (int dr = 0; dr < 4; ++dr) {
                float m = fmaxf(fmaxf(acc[mi][0][dr], acc[mi][1][dr]),
                                fmaxf(acc[mi][2][dr], acc[mi][3][dr]));
                m = fmaxf(m, __shfl_xor(m, 1, 64));
                m = fmaxf(m, __shfl_xor(m, 2, 64));
                m = fmaxf(m, __shfl_xor(m, 4, 64));
                m = fmaxf(m, __shfl_xor(m, 8, 64));
                float l = 0.f, sx = 0.f;
#pragma unroll
                for (int ni = 0; ni < 4; ++ni) {
                    float e = __expf((acc[mi][ni][dr] - m) * INV_BETA);
                    l += e;
                    sx += e * (-1.f + (float)(ni * 16 + lr) * STEP63);
                }
                l += __shfl_xor(l, 1, 64);  sx += __shfl_xor(sx, 1, 64);
                l += __shfl_xor(l, 2, 64);  sx += __shfl_xor(sx, 2, 64);
                l += __shfl_xor(l, 4, 64);  sx += __shfl_xor(sx, 4, 64);
                l += __shfl_xor(l, 8, 64);  sx += __shfl_xor(sx, 8, 64);
                if (lr == 0)
                    pred4[wc * 128 + wr * 64 + mi * 16 + lq * 4 + dr] = make_float4(m, l, sx, yn1 * l);
            }
    }
    __syncthreads();
    if (tid < 128) {
        float4 h0 = pred4[tid], h1 = pred4[128 + tid];
        float M = fmaxf(h0.x, h1.x);
        float s0 = __expf((h0.x - M) * INV_BETA);
        float s1 = __expf((h1.x - M) * INV_BETA);
        parts4[((size_t)b * 4096 + by * 128 + tid) * 32 + bx] =
            make_float4(M, h0.y * s0 + h1.y * s1, h0.z * s0 + h1.z * s1, h0.w * s0 + h1.w * s1);
    }
    __syncthreads();

    // f-direction: per col, reduce over this wave's 64 rows (lanes sharing lr)
    {
        float yn0 = -1.f + (float)(2 * by + wr) * STEP63;
#pragma unroll
        for (int ni = 0; ni < 4; ++ni) {
            float m = acc[0][ni][0];
#pragma unroll
            for (int mi = 0; mi < 4; ++mi)
#pragma unroll
                for (int dr = 0; dr < 4; ++dr) m = fmaxf(m, acc[mi][ni][dr]);
            m = fmaxf(m, __shfl_xor(m, 16, 64));
            m = fmaxf(m, __shfl_xor(m, 32, 64));
            float l = 0.f, sx = 0.f;
#pragma unroll
            for (int mi = 0; mi < 4; ++mi)
#pragma unroll
                for (int dr = 0; dr < 4; ++dr) {
                    float e = __expf((acc[mi][ni][dr] - m) * INV_BETA);
                    l += e;
                    sx += e * (-1.f + (float)(mi * 16 + lq * 4 + dr) * STEP63);
                }
            l += __shfl_xor(l, 16, 64);  sx += __shfl_xor(sx, 16, 64);
            l += __shfl_xor(l, 32, 64);  sx += __shfl_xor(sx, 32, 64);
            if (lq == 0)
                pred4[wr * 128 + wc * 64 + ni * 16 + lr] = make_float4(m, l, sx, yn0 * l);
        }
    }
    __syncthreads();
    if (tid < 128) {
        float4 h0 = pred4[tid], h1 = pred4[128 + tid];
        float M = fmaxf(h0.x, h1.x);
        float s0 = __expf((h0.x - M) * INV_BETA);
        float s1 = __expf((h1.x - M) * INV_BETA);
        parts4[262144 + ((size_t)b * 4096 + bx * 128 + tid) * 32 + by] =
            make_float4(M, h0.y * s0 + h1.y * s1, h0.z * s0 + h1.z * s1, h0.w * s0 + h1.w * s1);
    }
}

// ---------------------------------------------------------------------------
// k_flow: merge 32 partials per row -> flow values. One wave per row.
// ---------------------------------------------------------------------------
__global__ __launch_bounds__(256) void k_flow(const float* __restrict__ parts,
                                              float* __restrict__ flow,
                                              float* __restrict__ flowf) {
    const int row = blockIdx.x * 4 + (threadIdx.x >> 6);
    const int lane = threadIdx.x & 63;
    const float4* p4 = (const float4*)parts + (long long)row * 32;
    float m = -1e30f, l = 0.f, sx = 0.f, sy = 0.f;
    if (lane < 32) { float4 v = p4[lane]; m = v.x; l = v.y; sx = v.z; sy = v.w; }
    float M = m;
#pragma unroll
    for (int off = 1; off < 64; off <<= 1) M = fmaxf(M, __shfl_xor(M, off, 64));
    float s = __expf((m - M) * INV_BETA);
    l *= s; sx *= s; sy *= s;
#pragma unroll
    for (int off = 1; off < 64; off <<= 1) {
        l += __shfl_xor(l, off, 64);
        sx += __shfl_xor(sx, off, 64);
        sy += __shfl_xor(sy, off, 64);
    }
    if (lane == 0) {
        float gx = sx / l, gy = sy / l;
        float mx = (gx + 1.f) * 31.5f, my = (gy + 1.f) * 31.5f;
        int dir = row >> 13, b = (row >> 12) & 1, p = row & 4095;
        float* o = dir ? flowf : flow;
        o[(long long)b * 8192 + p] = mx - (float)(p & 63);
        o[(long long)b * 8192 + 4096 + p] = my - (float)(p >> 6);
    }
}

// ---------------------------------------------------------------------------
// trans_features = stack([f0f, f1f], axis=1)
// ---------------------------------------------------------------------------
__global__ void k_copy_trans(const float* __restrict__ f0f, const float* __restrict__ f1f,
                             float* __restrict__ out1) {
    int idx = blockIdx.x * 256 + threadIdx.x;
    int bv = idx >> 17;
    int r = idx & 131071;
    int b = bv >> 1, v = bv & 1;
    const float4* src = (const float4*)(v ? f1f : f0f) + (long long)b * 131072 + r;
    ((float4*)out1)[idx] = *src;
}

// ---------------------------------------------------------------------------
// trans_features_coarse: bilinear 32->64 of stacked feat_c
// ---------------------------------------------------------------------------
__global__ void k_coarse(const float* __restrict__ f0c, const float* __restrict__ f1c,
                         float* __restrict__ out2) {
    int idx = blockIdx.x * 256 + threadIdx.x;
    int x = idx & 63, y = (idx >> 6) & 63, ch = (idx >> 12) & 127;
    int v = (idx >> 19) & 1, b = idx >> 20;
    int iy0, iy1; float wy; interp_coef32(y, iy0, iy1, wy);
    int ix0, ix1; float wx; interp_coef32(x, ix0, ix1, wx);
    const float* src = (v ? f1c : f0c) + (long long)(b * 128 + ch) * 1024;
    float a  = src[iy0 * 32 + ix0] * (1.f - wy) + src[iy1 * 32 + ix0] * wy;
    float c2 = src[iy0 * 32 + ix1] * (1.f - wy) + src[iy1 * 32 + ix1] * wy;
    out2[idx] = a * (1.f - wx) + c2 * wx;
}

// ========================= fallback path (round-1) =========================
__global__ __launch_bounds__(256) void k_fused_fb(const float* __restrict__ f0f,
                                                  const float* __restrict__ f1f,
                                                  const float* __restrict__ cws,
                                                  float* __restrict__ c_out,
                                                  float* __restrict__ cf_out) {
    __shared__ float As[16][64];
    __shared__ float Bs[16][64];
    __shared__ float tmp[32][33];
    const int b = blockIdx.z, y0 = blockIdx.y, y1 = blockIdx.x;
    const int tid = threadIdx.x;
    const int tx = tid & 15, ty = tid >> 4;
    const float* A  = f0f + (long long)b * 524288 + y0 * 64;
    const float* Bp = f1f + (long long)b * 524288 + y1 * 64;
    int iy0a, iy0b; float wy0; interp_coef32(y0, iy0a, iy0b, wy0);
    int iy1a, iy1b; float wy1; interp_coef32(y1, iy1a, iy1b, wy1);
    const float* Cc = cws + (long long)b * 1048576;
    for (int r = tid; r < 1024; r += 256) {
        int i = r >> 5, j = r & 31;
        const float* ra = Cc + (long long)(iy0a * 32 + i) * 1024;
        const float* rb = Cc + (long long)(iy0b * 32 + i) * 1024;
        float va = ra[iy1a * 32 + j] * (1.f - wy1) + ra[iy1b * 32 + j] * wy1;
        float vb = rb[iy1a * 32 + j] * (1.f - wy1) + rb[iy1b * 32 + j] * wy1;
        tmp[i][j] = va * (1.f - wy0) + vb * wy0;
    }
    float acc[4][4] = {{0.f}};
    const int lk = tid >> 4;
    const int lc = (tid & 15) * 4;
    for (int k0 = 0; k0 < 128; k0 += 16) {
        *(float4*)&As[lk][lc] = *(const float4*)&A[(long long)(k0 + lk) * 4096 + lc];
        *(float4*)&Bs[lk][lc] = *(const float4*)&Bp[(long long)(k0 + lk) * 4096 + lc];
        __syncthreads();
#pragma unroll
        for (int kk = 0; kk < 16; ++kk) {
            float4 a4 = *(float4*)&As[kk][ty * 4];
            float4 b4 = *(float4*)&Bs[kk][tx * 4];
            float av[4] = {a4.x, a4.y, a4.z, a4.w};
            float bv[4] = {b4.x, b4.y, b4.z, b4.w};
#pragma unroll
            for (int i = 0; i < 4; ++i)
#pragma unroll
                for (int j = 0; j < 4; ++j)
                    acc[i][j] = fmaf(av[i], bv[j], acc[i][j]);
        }
        __syncthreads();
    }
    int ix0a[4], ix0b[4]; float wx0[4];
    int ix1a[4], ix1b[4]; float wx1[4];
#pragma unroll
    for (int i = 0; i < 4; ++i) interp_coef32(ty * 4 + i, ix0a[i], ix0b[i], wx0[i]);
#pragma unroll
    for (int j = 0; j < 4; ++j) interp_coef32(tx * 4 + j, ix1a[j], ix1b[j], wx1[j]);
    float val[4][4];
#pragma unroll
    for (int i = 0; i < 4; ++i)
#pragma unroll
        for (int j = 0; j < 4; ++j) {
            float ta = tmp[ix0a[i]][ix1a[j]] * (1.f - wx1[j]) + tmp[ix0a[i]][ix1b[j]] * wx1[j];
            float tb = tmp[ix0b[i]][ix1a[j]] * (1.f - wx1[j]) + tmp[ix0b[i]][ix1b[j]] * wx1[j];
            val[i][j] = (acc[i][j] * SCALE_C + (ta * (1.f - wx0[i]) + tb * wx0[i])) * 0.5f;
        }
    const long long cbase = ((long long)b << 24) + (long long)(y0 * 64) * 4096 + y1 * 64;
#pragma unroll
    for (int i = 0; i < 4; ++i)
        *(float4*)&c_out[cbase + (long long)(ty * 4 + i) * 4096 + tx * 4] =
            make_float4(val[i][0], val[i][1], val[i][2], val[i][3]);
    const long long fbase = ((long long)b << 24) + (long long)(y1 * 64) * 4096 + y0 * 64;
#pragma unroll
    for (int j = 0; j < 4; ++j)
        *(float4*)&cf_out[fbase + (long long)(tx * 4 + j) * 4096 + ty * 4] =
            make_float4(val[0][j], val[1][j], val[2][j], val[3][j]);
}

__global__ __launch_bounds__(256) void k_softargmax(const float* __restrict__ cmat,
                                                    float* __restrict__ flow_out) {
    const int tid = threadIdx.x;
    const float4* src = (const float4*)cmat + (long long)blockIdx.x * 1024;
    float4 r0 = src[tid];
    float4 r1 = src[tid + 256];
    float4 r2 = src[tid + 512];
    float4 r3 = src[tid + 768];
    float m = fmaxf(fmaxf(fmaxf(r0.x, r0.y), fmaxf(r0.z, r0.w)),
                    fmaxf(fmaxf(r1.x, r1.y), fmaxf(r1.z, r1.w)));
    m = fmaxf(m, fmaxf(fmaxf(r2.x, r2.y), fmaxf(r2.z, r2.w)));
    m = fmaxf(m, fmaxf(fmaxf(r3.x, r3.y), fmaxf(r3.z, r3.w)));
    __shared__ float red[16];
    const int lane = tid & 63, wave = tid >> 6;
#pragma unroll
    for (int off = 32; off > 0; off >>= 1) m = fmaxf(m, __shfl_xor(m, off, 64));
    if (lane == 0) red[wave] = m;
    __syncthreads();
    m = fmaxf(fmaxf(red[0], red[1]), fmaxf(red[2], red[3]));
    float l = 0.f, sx = 0.f, sy = 0.f;
#pragma unroll
    for (int s = 0; s < 4; ++s) {
        float4 r = (s == 0) ? r0 : (s == 1) ? r1 : (s == 2) ? r2 : r3;
        int f = tid + s * 256;
        float yn = -1.f + (float)(f >> 4) * STEP63;
        float xb = (float)((f & 15) * 4);
        float e0 = __expf((r.x - m) * 50.f);
        float e1 = __expf((r.y - m) * 50.f);
        float e2 = __expf((r.z - m) * 50.f);
        float e3 = __expf((r.w - m) * 50.f);
        float es = e0 + e1 + e2 + e3;
        l += es;
        sy += es * yn;
        sx += e0 * (-1.f + xb * STEP63) + e1 * (-1.f + (xb + 1.f) * STEP63)
            + e2 * (-1.f + (xb + 2.f) * STEP63) + e3 * (-1.f + (xb + 3.f) * STEP63);
    }
#pragma unroll
    for (int off = 32; off > 0; off >>= 1) {
        l  += __shfl_xor(l, off, 64);
        sx += __shfl_xor(sx, off, 64);
        sy += __shfl_xor(sy, off, 64);
    }
    if (lane == 0) { red[4 + wave] = l; red[8 + wave] = sx; red[12 + wave] = sy; }
    __syncthreads();
    if (tid == 0) {
        float L  = red[4] + red[5] + red[6] + red[7];
        float SX = red[8] + red[9] + red[10] + red[11];
        float SY = red[12] + red[13] + red[14] + red[15];
        float mx = (SX / L + 1.f) * 31.5f;
        float my = (SY / L + 1.f) * 31.5f;
        int bi = blockIdx.x;
        int b = bi >> 12, p = bi & 4095;
        flow_out[(long long)b * 8192 + p]        = mx - (float)(p & 63);
        flow_out[(long long)b * 8192 + 4096 + p] = my - (float)(p >> 6);
    }
}

// ---------------------------------------------------------------------------
// Output layout (floats): trans_features @0 | coarse @2,097,152 | c @4,194,304
// | c_flip @37,748,736 | flow @71,303,168 | flow_flip @71,319,552
// Fast path stages bf16 hi/lo planes (8 MB) in the trans_features region;
// k_copy_trans rewrites it afterwards (stream-ordered).
// ---------------------------------------------------------------------------
extern "C" void kernel_launch(void* const* d_in, const int* in_sizes, int n_in,
                              void* d_out, int out_size, void* d_ws, size_t ws_size,
                              hipStream_t stream) {
    const float* f0c = (const float*)d_in[0];
    const float* f1c = (const float*)d_in[1];
    const float* f0f = (const float*)d_in[2];
    const float* f1f = (const float*)d_in[3];
    float* out = (float*)d_out;

    float* c_out  = out + 4194304;
    float* cf_out = out + 37748736;
    float* flow   = out + 71303168;
    float* flowf  = out + 71319552;

    if (ws_size >= (size_t)16777216) {
        float* parts = (float*)d_ws;          // 2,097,152 floats (8 MB): softmax partials
        float* cws   = parts + 2097152;       // 2,097,152 floats (8 MB): coarse corr
        unsigned short* hi = (unsigned short*)out;          // 4 planes x [4096][128] bf16
        unsigned short* lo = hi + 2097152;                  // matching lo planes
        k_split<<<dim3(64, 4, 1), 256, 0, stream>>>(f0f, f1f, hi, lo);
        k_corr_c<<<dim3(16, 16, 2), 256, 0, stream>>>(f0c, f1c, cws);
        k_fused2<<<dim3(32, 32, 2), 256, 0, stream>>>(hi, cws, c_out, cf_out, parts);
        k_flow<<<4096, 256, 0, stream>>>(parts, flow, flowf);
        k_copy_trans<<<2048, 256, 0, stream>>>(f0f, f1f, out);   // overwrites plane staging
        k_coarse<<<8192, 256, 0, stream>>>(f0c, f1c, out + 2097152);
    } else {
        float* corr_ws = out;                 // reuse trans_features region as scratch
        k_corr_c<<<dim3(16, 16, 2), 256, 0, stream>>>(f0c, f1c, corr_ws);
        k_fused_fb<<<dim3(64, 64, 2), 256, 0, stream>>>(f0f, f1f, corr_ws, c_out, cf_out);
        k_copy_trans<<<2048, 256, 0, stream>>>(f0f, f1f, out);
        k_coarse<<<8192, 256, 0, stream>>>(f0c, f1c, out + 2097152);
        k_softargmax<<<8192, 256, 0, stream>>>(c_out, flow);
        k_softargmax<<<8192, 256, 0, stream>>>(cf_out, flowf);
    }
}

// Round 4
// 408.030 us; speedup vs baseline: 1.1129x; 1.0006x over previous
//
#include <hip/hip_runtime.h>
#include <math.h>

#define SCALE_C 0.08838834764831845f  // 1/sqrt(128)
#define INV_BETA 50.0f
#define STEP63 (2.0f / 63.0f)

typedef short bf16x8 __attribute__((ext_vector_type(8)));
typedef float f32x4 __attribute__((ext_vector_type(4)));

// align_corners bilinear coefficients for 32 -> 64 (src = t*31/63)
__device__ __forceinline__ void interp_coef32(int t, int& i0, int& i1, float& w) {
    float s = (float)(t * 31) / 63.0f;
    i0 = (int)floorf(s);
    if (i0 > 31) i0 = 31;
    i1 = i0 + 1;
    if (i1 > 31) i1 = 31;
    w = s - (float)i0;
}

// ---------------------------------------------------------------------------
// corr_c: [b,1024,1024] = f0c^T f1c / sqrt(128). 64x64 tile per block.
// ---------------------------------------------------------------------------
__global__ __launch_bounds__(256) void k_corr_c(const float* __restrict__ f0c,
                                                const float* __restrict__ f1c,
                                                float* __restrict__ ws) {
    __shared__ float As[16][64];
    __shared__ float Bs[16][64];
    const int b = blockIdx.z;
    const int m0 = blockIdx.y * 64, n0 = blockIdx.x * 64;
    const float* A  = f0c + (long long)b * 131072;
    const float* Bp = f1c + (long long)b * 131072;
    const int tid = threadIdx.x;
    const int tx = tid & 15, ty = tid >> 4;
    const int lk = tid >> 4;
    const int lc = (tid & 15) * 4;
    float acc[4][4] = {{0.f}};
    for (int k0 = 0; k0 < 128; k0 += 16) {
        *(float4*)&As[lk][lc] = *(const float4*)&A[(k0 + lk) * 1024 + m0 + lc];
        *(float4*)&Bs[lk][lc] = *(const float4*)&Bp[(k0 + lk) * 1024 + n0 + lc];
        __syncthreads();
#pragma unroll
        for (int kk = 0; kk < 16; ++kk) {
            float4 a4 = *(float4*)&As[kk][ty * 4];
            float4 b4 = *(float4*)&Bs[kk][tx * 4];
            float av[4] = {a4.x, a4.y, a4.z, a4.w};
            float bv[4] = {b4.x, b4.y, b4.z, b4.w};
#pragma unroll
            for (int i = 0; i < 4; ++i)
#pragma unroll
                for (int j = 0; j < 4; ++j)
                    acc[i][j] = fmaf(av[i], bv[j], acc[i][j]);
        }
        __syncthreads();
    }
#pragma unroll
    for (int i = 0; i < 4; ++i) {
        float4 w4 = make_float4(acc[i][0] * SCALE_C, acc[i][1] * SCALE_C,
                                acc[i][2] * SCALE_C, acc[i][3] * SCALE_C);
        *(float4*)&ws[(long long)b * 1048576 + (long long)(m0 + ty * 4 + i) * 1024 + n0 + tx * 4] = w4;
    }
}

// ---------------------------------------------------------------------------
// k_split: fp32 [mat][128 k][4096 pix] -> bf16 hi/lo planes [mat][pix][128 k].
// ---------------------------------------------------------------------------
__global__ __launch_bounds__(256) void k_split(const float* __restrict__ f0f,
                                               const float* __restrict__ f1f,
                                               unsigned short* __restrict__ hi,
                                               unsigned short* __restrict__ lo) {
    __shared__ unsigned int t[64 * 132];   // packed (hi | lo<<16), [pix][k] stride 132
    const int m = blockIdx.y;              // plane: 0,1 = f0f b0,b1; 2,3 = f1f b0,b1
    const int pt = blockIdx.x;             // pixel tile (64 pix)
    const float* src = ((m >> 1) ? f1f : f0f) + (size_t)(m & 1) * 524288 + pt * 64;
    const int tid = threadIdx.x;
#pragma unroll
    for (int p = 0; p < 8; ++p) {
        int k = p * 16 + (tid >> 4);
        int px = (tid & 15) * 4;
        float4 v = *(const float4*)&src[(size_t)k * 4096 + px];
        float vv[4] = {v.x, v.y, v.z, v.w};
#pragma unroll
        for (int j = 0; j < 4; ++j) {
            float x = vv[j];
            unsigned int u = __float_as_uint(x);
            unsigned int h = (u + 0x7FFFu + ((u >> 16) & 1u)) >> 16;     // RNE bf16
            float r = x - __uint_as_float(h << 16);                      // exact
            unsigned int ur = __float_as_uint(r);
            unsigned int l2 = (ur + 0x7FFFu + ((ur >> 16) & 1u)) >> 16;  // RNE bf16
            t[(px + j) * 132 + k] = h | (l2 << 16);
        }
    }
    __syncthreads();
    const int row = tid >> 2, ks = (tid & 3) * 32;
    size_t obase = ((size_t)m * 4096 + (size_t)pt * 64 + row) * 128 + ks;
#pragma unroll
    for (int c = 0; c < 4; ++c) {
        unsigned int u[8];
        *(uint4*)&u[0] = *(const uint4*)&t[row * 132 + ks + c * 8];
        *(uint4*)&u[4] = *(const uint4*)&t[row * 132 + ks + c * 8 + 4];
        uint4 ho, lw;
        ho.x = (u[0] & 0xFFFFu) | (u[1] << 16);
        ho.y = (u[2] & 0xFFFFu) | (u[3] << 16);
        ho.z = (u[4] & 0xFFFFu) | (u[5] << 16);
        ho.w = (u[6] & 0xFFFFu) | (u[7] << 16);
        lw.x = (u[0] >> 16) | (u[1] & 0xFFFF0000u);
        lw.y = (u[2] >> 16) | (u[3] & 0xFFFF0000u);
        lw.z = (u[4] >> 16) | (u[5] & 0xFFFF0000u);
        lw.w = (u[6] >> 16) | (u[7] & 0xFFFF0000u);
        *(uint4*)&hi[obase + c * 8] = ho;
        *(uint4*)&lo[obase + c * 8] = lw;
    }
}

// ---------------------------------------------------------------------------
// k_fused2: 128x128 tile of the 4096x4096 GEMM (K=128) via split-bf16 3-pass
// mfma_f32_16x16x32_bf16. 4 waves, each owns a 64x64 sub-tile.
// GEMM loop is A-resident / B-streamed to keep peak VGPR liveness ~160:
//   per kc: ah[4],al[4] resident; per ni: load bh,bl; 12 MFMAs.
// launch_bounds (256,2): do NOT force a 168-reg cap that spills acc/fragments
// to scratch (the round-1..3 hidden cost). LDS 53.76 KB still allows
// 3 blocks/CU if the allocator lands <=170 VGPR.
// ---------------------------------------------------------------------------
__global__ __launch_bounds__(256, 2) void k_fused2(const unsigned short* __restrict__ planes,
                                                   const float* __restrict__ cws,
                                                   float* __restrict__ c_out,
                                                   float* __restrict__ cf_out,
                                                   float* __restrict__ parts) {
    __shared__ __attribute__((aligned(16))) float smem[13440];
    float* const Freg = smem + 9216;        // F[4][32][33]
    const int b = blockIdx.z, by = blockIdx.y, bx = blockIdx.x;
    const int tid = threadIdx.x;
    const int wv = tid >> 6, lane = tid & 63;
    const int lr = lane & 15, lq = lane >> 4;
    const int wr = wv >> 1, wc = wv & 1;

    const int y0base = (2 * by * 31) / 63;
    const int y1base = (2 * bx * 31) / 63;

    // ---- stage A: coarse sub-block SA[dy0][x0c][dy1][x1c] (linear = e) ----
    {
        const float* Cc = cws + (size_t)b * 1048576;
        for (int e = tid; e < 9216; e += 256) {
            int x1c = e & 31;
            int q = e >> 5;                         // 0..287
            int r = (q * 21846) >> 16;              // q/3
            int dy1 = q - r * 3;
            int x0c = r & 31;
            int dy0 = r >> 5;
            int y0r = y0base + dy0; if (y0r > 31) y0r = 31;
            int y1r = y1base + dy1; if (y1r > 31) y1r = 31;
            smem[e] = Cc[(size_t)(y0r * 32 + x0c) * 1024 + y1r * 32 + x1c];
        }
    }
    __syncthreads();

    // ---- stage B: F[p][x0c][x1c] = y0,y1 interp from SA ----
    {
        for (int e = tid; e < 4096; e += 256) {
            int x1c = e & 31, x0c = (e >> 5) & 31, p = e >> 10;
            int s0 = p >> 1, s1 = p & 1;
            int ya, yb; float wy0; interp_coef32(2 * by + s0, ya, yb, wy0);
            int za, zb; float wy1; interp_coef32(2 * bx + s1, za, zb, wy1);
            int a0 = ya - y0base, a1 = yb - y0base;
            int b0 = za - y1base, b1 = zb - y1base;
            const float* s00 = &smem[((a0 * 32 + x0c) * 3) * 32 + x1c];
            const float* s10 = &smem[((a1 * 32 + x0c) * 3) * 32 + x1c];
            float g0 = s00[b0 * 32] * (1.f - wy1) + s00[b1 * 32] * wy1;
            float g1 = s10[b0 * 32] * (1.f - wy1) + s10[b1 * 32] * wy1;
            Freg[(p * 32 + x0c) * 33 + x1c] = g0 * (1.f - wy0) + g1 * wy0;
        }
    }
    __syncthreads();   // F done; SA dead (t2 overwrites region0)

    // ---- stage C: t2[p][x1][x0c] = x1 interp of F ----
    {
        for (int e = tid; e < 8192; e += 256) {
            int x1 = e & 63, x0c = (e >> 6) & 31, p = e >> 11;
            int xa, xb; float wx1; interp_coef32(x1, xa, xb, wx1);
            const float* Fp = &Freg[(p * 32 + x0c) * 33];
            smem[(p * 64 + x1) * 33 + x0c] = Fp[xa] * (1.f - wx1) + Fp[xb] * wx1;
        }
    }

    // ---- split-bf16 MFMA GEMM (no LDS involved; A-resident, B-streamed) ----
    const unsigned short* Ah = planes + (size_t)b * 524288       + (size_t)(by * 128 + wr * 64) * 128;
    const unsigned short* Bh = planes + (size_t)(2 + b) * 524288 + (size_t)(bx * 128 + wc * 64) * 128;
    f32x4 acc[4][4];
#pragma unroll
    for (int i = 0; i < 4; ++i)
#pragma unroll
        for (int j = 0; j < 4; ++j) acc[i][j] = (f32x4){0.f, 0.f, 0.f, 0.f};

#pragma unroll 1
    for (int kc = 0; kc < 4; ++kc) {
        const int ko = kc * 32 + lq * 8;
        bf16x8 ah[4], al[4];
#pragma unroll
        for (int t = 0; t < 4; ++t) {
            const unsigned short* pa = Ah + (size_t)(t * 16 + lr) * 128 + ko;
            ah[t] = *(const bf16x8*)pa;
            al[t] = *(const bf16x8*)(pa + 2097152);   // lo planes follow hi planes
        }
#pragma unroll
        for (int ni = 0; ni < 4; ++ni) {
            const unsigned short* pb = Bh + (size_t)(ni * 16 + lr) * 128 + ko;
            bf16x8 bh = *(const bf16x8*)pb;
            bf16x8 bl = *(const bf16x8*)(pb + 2097152);
#pragma unroll
            for (int mi = 0; mi < 4; ++mi) {
                f32x4 a = acc[mi][ni];
                a = __builtin_amdgcn_mfma_f32_16x16x32_bf16(ah[mi], bh, a, 0, 0, 0);
                a = __builtin_amdgcn_mfma_f32_16x16x32_bf16(al[mi], bh, a, 0, 0, 0);
                a = __builtin_amdgcn_mfma_f32_16x16x32_bf16(ah[mi], bl, a, 0, 0, 0);
                acc[mi][ni] = a;
            }
        }
    }

    __syncthreads();   // t2 fully written before epilogue reads

    // ---- epilogue: x0-interp of coarse + combine ----
#pragma unroll
    for (int mi = 0; mi < 4; ++mi)
#pragma unroll
        for (int dr = 0; dr < 4; ++dr) {
            int x0 = mi * 16 + lq * 4 + dr;
            float s = (float)(x0 * 31) / 63.0f;
            int i0 = (int)s;
            float w = s - (float)i0;
            int i1 = i0 + 1; if (i1 > 31) i1 = 31;
#pragma unroll
            for (int ni = 0; ni < 4; ++ni) {
                const float* t2 = &smem[(wv * 64 + ni * 16 + lr) * 33];
                float up = t2[i0] * (1.f - w) + t2[i1] * w;
                acc[mi][ni][dr] = (acc[mi][ni][dr] * SCALE_C + up) * 0.5f;
            }
        }

    // ---- c stores: 2-round LDS transpose -> coalesced float4 rows ----
#pragma unroll
    for (int r = 0; r < 2; ++r) {
        __syncthreads();   // t2/previous-round reads done
        if (wr == r) {
#pragma unroll
            for (int mi = 0; mi < 4; ++mi)
#pragma unroll
                for (int dr = 0; dr < 4; ++dr) {
                    int rl = mi * 16 + lq * 4 + dr;
                    int sw = (rl & 7) << 2;
#pragma unroll
                    for (int ni = 0; ni < 4; ++ni) {
                        int col = wc * 64 + ni * 16 + lr;
                        int c4 = col >> 2;
                        smem[rl * 132 + ((c4 ^ sw) << 2) + (col & 3)] = acc[mi][ni][dr];
                    }
                }
        }
        __syncthreads();
        size_t cb = ((size_t)b << 24) + (size_t)(by * 128 + r * 64) * 4096 + bx * 128;
#pragma unroll
        for (int i = 0; i < 8; ++i) {
            int f = tid + i * 256;          // [0,2048)
            int rl = f >> 5, c4 = f & 31;
            float4 v = *(float4*)&smem[rl * 132 + ((c4 ^ ((rl & 7) << 2)) << 2)];
            *(float4*)&c_out[cb + (size_t)rl * 4096 + c4 * 4] = v;
        }
    }

    // ---- c_flip stores: 2-round LDS transpose (rows of cf = tile cols) ----
#pragma unroll
    for (int r = 0; r < 2; ++r) {
        __syncthreads();   // previous-round reads done
        if (wc == r) {
#pragma unroll
            for (int ni = 0; ni < 4; ++ni) {
                int col = ni * 16 + lr;     // local col within this half
                int sw = (col & 7) << 2;
#pragma unroll
                for (int mi = 0; mi < 4; ++mi) {
                    int q = wr * 16 + mi * 4 + lq;   // row-quad in [0,32)
                    *(float4*)&smem[col * 132 + ((q ^ sw) << 2)] =
                        make_float4(acc[mi][ni][0], acc[mi][ni][1], acc[mi][ni][2], acc[mi][ni][3]);
                }
            }
        }
        __syncthreads();
        size_t fb = ((size_t)b << 24) + (size_t)(bx * 128 + r * 64) * 4096 + by * 128;
#pragma unroll
        for (int i = 0; i < 8; ++i) {
            int f = tid + i * 256;          // [0,2048)
            int col = f >> 5, q = f & 31;
            float4 v = *(float4*)&smem[col * 132 + ((q ^ ((col & 7) << 2)) << 2)];
            *(float4*)&cf_out[fb + (size_t)col * 4096 + q * 4] = v;
        }
    }

    // ---- softmax partials ----
    float4* pred4 = (float4*)smem;
    float4* parts4 = (float4*)parts;
    __syncthreads();   // transpose reads done; reuse LDS as pred4

    // c-direction: per row, reduce over this wave's 64 cols (lanes sharing lq)
    {
        float yn1 = -1.f + (float)(2 * bx + wc) * STEP63;
#pragma unroll
        for (int mi = 0; mi < 4; ++mi)
#pragma unroll
            for (int dr = 0; dr < 4; ++dr) {
                float m = fmaxf(fmaxf(acc[mi][0][dr], acc[mi][1][dr]),
                                fmaxf(acc[mi][2][dr], acc[mi][3][dr]));
                m = fmaxf(m, __shfl_xor(m, 1, 64));
                m = fmaxf(m, __shfl_xor(m, 2, 64));
                m = fmaxf(m, __shfl_xor(m, 4, 64));
                m = fmaxf(m, __shfl_xor(m, 8, 64));
                float l = 0.f, sx = 0.f;
#pragma unroll
                for (int ni = 0; ni < 4; ++ni) {
                    float e = __expf((acc[mi][ni][dr] - m) * INV_BETA);
                    l += e;
                    sx += e * (-1.f + (float)(ni * 16 + lr) * STEP63);
                }
                l += __shfl_xor(l, 1, 64);  sx += __shfl_xor(sx, 1, 64);
                l += __shfl_xor(l, 2, 64);  sx += __shfl_xor(sx, 2, 64);
                l += __shfl_xor(l, 4, 64);  sx += __shfl_xor(sx, 4, 64);
                l += __shfl_xor(l, 8, 64);  sx += __shfl_xor(sx, 8, 64);
                if (lr == 0)
                    pred4[wc * 128 + wr * 64 + mi * 16 + lq * 4 + dr] = make_float4(m, l, sx, yn1 * l);
            }
    }
    __syncthreads();
    if (tid < 128) {
        float4 h0 = pred4[tid], h1 = pred4[128 + tid];
        float M = fmaxf(h0.x, h1.x);
        float s0 = __expf((h0.x - M) * INV_BETA);
        float s1 = __expf((h1.x - M) * INV_BETA);
        parts4[((size_t)b * 4096 + by * 128 + tid) * 32 + bx] =
            make_float4(M, h0.y * s0 + h1.y * s1, h0.z * s0 + h1.z * s1, h0.w * s0 + h1.w * s1);
    }
    __syncthreads();

    // f-direction: per col, reduce over this wave's 64 rows (lanes sharing lr)
    {
        float yn0 = -1.f + (float)(2 * by + wr) * STEP63;
#pragma unroll
        for (int ni = 0; ni < 4; ++ni) {
            float m = acc[0][ni][0];
#pragma unroll
            for (int mi = 0; mi < 4; ++mi)
#pragma unroll
                for (int dr = 0; dr < 4; ++dr) m = fmaxf(m, acc[mi][ni][dr]);
            m = fmaxf(m, __shfl_xor(m, 16, 64));
            m = fmaxf(m, __shfl_xor(m, 32, 64));
            float l = 0.f, sx = 0.f;
#pragma unroll
            for (int mi = 0; mi < 4; ++mi)
#pragma unroll
                for (int dr = 0; dr < 4; ++dr) {
                    float e = __expf((acc[mi][ni][dr] - m) * INV_BETA);
                    l += e;
                    sx += e * (-1.f + (float)(mi * 16 + lq * 4 + dr) * STEP63);
                }
            l += __shfl_xor(l, 16, 64);  sx += __shfl_xor(sx, 16, 64);
            l += __shfl_xor(l, 32, 64);  sx += __shfl_xor(sx, 32, 64);
            if (lq == 0)
                pred4[wr * 128 + wc * 64 + ni * 16 + lr] = make_float4(m, l, sx, yn0 * l);
        }
    }
    __syncthreads();
    if (tid < 128) {
        float4 h0 = pred4[tid], h1 = pred4[128 + tid];
        float M = fmaxf(h0.x, h1.x);
        float s0 = __expf((h0.x - M) * INV_BETA);
        float s1 = __expf((h1.x - M) * INV_BETA);
        parts4[262144 + ((size_t)b * 4096 + bx * 128 + tid) * 32 + by] =
            make_float4(M, h0.y * s0 + h1.y * s1, h0.z * s0 + h1.z * s1, h0.w * s0 + h1.w * s1);
    }
}

// ---------------------------------------------------------------------------
// k_flow: merge 32 partials per row -> flow values. One wave per row.
// ---------------------------------------------------------------------------
__global__ __launch_bounds__(256) void k_flow(const float* __restrict__ parts,
                                              float* __restrict__ flow,
                                              float* __restrict__ flowf) {
    const int row = blockIdx.x * 4 + (threadIdx.x >> 6);
    const int lane = threadIdx.x & 63;
    const float4* p4 = (const float4*)parts + (long long)row * 32;
    float m = -1e30f, l = 0.f, sx = 0.f, sy = 0.f;
    if (lane < 32) { float4 v = p4[lane]; m = v.x; l = v.y; sx = v.z; sy = v.w; }
    float M = m;
#pragma unroll
    for (int off = 1; off < 64; off <<= 1) M = fmaxf(M, __shfl_xor(M, off, 64));
    float s = __expf((m - M) * INV_BETA);
    l *= s; sx *= s; sy *= s;
#pragma unroll
    for (int off = 1; off < 64; off <<= 1) {
        l += __shfl_xor(l, off, 64);
        sx += __shfl_xor(sx, off, 64);
        sy += __shfl_xor(sy, off, 64);
    }
    if (lane == 0) {
        float gx = sx / l, gy = sy / l;
        float mx = (gx + 1.f) * 31.5f, my = (gy + 1.f) * 31.5f;
        int dir = row >> 13, b = (row >> 12) & 1, p = row & 4095;
        float* o = dir ? flowf : flow;
        o[(long long)b * 8192 + p] = mx - (float)(p & 63);
        o[(long long)b * 8192 + 4096 + p] = my - (float)(p >> 6);
    }
}

// ---------------------------------------------------------------------------
// trans_features = stack([f0f, f1f], axis=1)
// ---------------------------------------------------------------------------
__global__ void k_copy_trans(const float* __restrict__ f0f, const float* __restrict__ f1f,
                             float* __restrict__ out1) {
    int idx = blockIdx.x * 256 + threadIdx.x;
    int bv = idx >> 17;
    int r = idx & 131071;
    int b = bv >> 1, v = bv & 1;
    const float4* src = (const float4*)(v ? f1f : f0f) + (long long)b * 131072 + r;
    ((float4*)out1)[idx] = *src;
}

// ---------------------------------------------------------------------------
// trans_features_coarse: bilinear 32->64 of stacked feat_c
// ---------------------------------------------------------------------------
__global__ void k_coarse(const float* __restrict__ f0c, const float* __restrict__ f1c,
                         float* __restrict__ out2) {
    int idx = blockIdx.x * 256 + threadIdx.x;
    int x = idx & 63, y = (idx >> 6) & 63, ch = (idx >> 12) & 127;
    int v = (idx >> 19) & 1, b = idx >> 20;
    int iy0, iy1; float wy; interp_coef32(y, iy0, iy1, wy);
    int ix0, ix1; float wx; interp_coef32(x, ix0, ix1, wx);
    const float* src = (v ? f1c : f0c) + (long long)(b * 128 + ch) * 1024;
    float a  = src[iy0 * 32 + ix0] * (1.f - wy) + src[iy1 * 32 + ix0] * wy;
    float c2 = src[iy0 * 32 + ix1] * (1.f - wy) + src[iy1 * 32 + ix1] * wy;
    out2[idx] = a * (1.f - wx) + c2 * wx;
}

// ========================= fallback path (round-1) =========================
__global__ __launch_bounds__(256) void k_fused_fb(const float* __restrict__ f0f,
                                                  const float* __restrict__ f1f,
                                                  const float* __restrict__ cws,
                                                  float* __restrict__ c_out,
                                                  float* __restrict__ cf_out) {
    __shared__ float As[16][64];
    __shared__ float Bs[16][64];
    __shared__ float tmp[32][33];
    const int b = blockIdx.z, y0 = blockIdx.y, y1 = blockIdx.x;
    const int tid = threadIdx.x;
    const int tx = tid & 15, ty = tid >> 4;
    const float* A  = f0f + (long long)b * 524288 + y0 * 64;
    const float* Bp = f1f + (long long)b * 524288 + y1 * 64;
    int iy0a, iy0b; float wy0; interp_coef32(y0, iy0a, iy0b, wy0);
    int iy1a, iy1b; float wy1; interp_coef32(y1, iy1a, iy1b, wy1);
    const float* Cc = cws + (long long)b * 1048576;
    for (int r = tid; r < 1024; r += 256) {
        int i = r >> 5, j = r & 31;
        const float* ra = Cc + (long long)(iy0a * 32 + i) * 1024;
        const float* rb = Cc + (long long)(iy0b * 32 + i) * 1024;
        float va = ra[iy1a * 32 + j] * (1.f - wy1) + ra[iy1b * 32 + j] * wy1;
        float vb = rb[iy1a * 32 + j] * (1.f - wy1) + rb[iy1b * 32 + j] * wy1;
        tmp[i][j] = va * (1.f - wy0) + vb * wy0;
    }
    float acc[4][4] = {{0.f}};
    const int lk = tid >> 4;
    const int lc = (tid & 15) * 4;
    for (int k0 = 0; k0 < 128; k0 += 16) {
        *(float4*)&As[lk][lc] = *(const float4*)&A[(long long)(k0 + lk) * 4096 + lc];
        *(float4*)&Bs[lk][lc] = *(const float4*)&Bp[(long long)(k0 + lk) * 4096 + lc];
        __syncthreads();
#pragma unroll
        for (int kk = 0; kk < 16; ++kk) {
            float4 a4 = *(float4*)&As[kk][ty * 4];
            float4 b4 = *(float4*)&Bs[kk][tx * 4];
            float av[4] = {a4.x, a4.y, a4.z, a4.w};
            float bv[4] = {b4.x, b4.y, b4.z, b4.w};
#pragma unroll
            for (int i = 0; i < 4; ++i)
#pragma unroll
                for (int j = 0; j < 4; ++j)
                    acc[i][j] = fmaf(av[i], bv[j], acc[i][j]);
        }
        __syncthreads();
    }
    int ix0a[4], ix0b[4]; float wx0[4];
    int ix1a[4], ix1b[4]; float wx1[4];
#pragma unroll
    for (int i = 0; i < 4; ++i) interp_coef32(ty * 4 + i, ix0a[i], ix0b[i], wx0[i]);
#pragma unroll
    for (int j = 0; j < 4; ++j) interp_coef32(tx * 4 + j, ix1a[j], ix1b[j], wx1[j]);
    float val[4][4];
#pragma unroll
    for (int i = 0; i < 4; ++i)
#pragma unroll
        for (int j = 0; j < 4; ++j) {
            float ta = tmp[ix0a[i]][ix1a[j]] * (1.f - wx1[j]) + tmp[ix0a[i]][ix1b[j]] * wx1[j];
            float tb = tmp[ix0b[i]][ix1a[j]] * (1.f - wx1[j]) + tmp[ix0b[i]][ix1b[j]] * wx1[j];
            val[i][j] = (acc[i][j] * SCALE_C + (ta * (1.f - wx0[i]) + tb * wx0[i])) * 0.5f;
        }
    const long long cbase = ((long long)b << 24) + (long long)(y0 * 64) * 4096 + y1 * 64;
#pragma unroll
    for (int i = 0; i < 4; ++i)
        *(float4*)&c_out[cbase + (long long)(ty * 4 + i) * 4096 + tx * 4] =
            make_float4(val[i][0], val[i][1], val[i][2], val[i][3]);
    const long long fbase = ((long long)b << 24) + (long long)(y1 * 64) * 4096 + y0 * 64;
#pragma unroll
    for (int j = 0; j < 4; ++j)
        *(float4*)&cf_out[fbase + (long long)(tx * 4 + j) * 4096 + ty * 4] =
            make_float4(val[0][j], val[1][j], val[2][j], val[3][j]);
}

__global__ __launch_bounds__(256) void k_softargmax(const float* __restrict__ cmat,
                                                    float* __restrict__ flow_out) {
    const int tid = threadIdx.x;
    const float4* src = (const float4*)cmat + (long long)blockIdx.x * 1024;
    float4 r0 = src[tid];
    float4 r1 = src[tid + 256];
    float4 r2 = src[tid + 512];
    float4 r3 = src[tid + 768];
    float m = fmaxf(fmaxf(fmaxf(r0.x, r0.y), fmaxf(r0.z, r0.w)),
                    fmaxf(fmaxf(r1.x, r1.y), fmaxf(r1.z, r1.w)));
    m = fmaxf(m, fmaxf(fmaxf(r2.x, r2.y), fmaxf(r2.z, r2.w)));
    m = fmaxf(m, fmaxf(fmaxf(r3.x, r3.y), fmaxf(r3.z, r3.w)));
    __shared__ float red[16];
    const int lane = tid & 63, wave = tid >> 6;
#pragma unroll
    for (int off = 32; off > 0; off >>= 1) m = fmaxf(m, __shfl_xor(m, off, 64));
    if (lane == 0) red[wave] = m;
    __syncthreads();
    m = fmaxf(fmaxf(red[0], red[1]), fmaxf(red[2], red[3]));
    float l = 0.f, sx = 0.f, sy = 0.f;
#pragma unroll
    for (int s = 0; s < 4; ++s) {
        float4 r = (s == 0) ? r0 : (s == 1) ? r1 : (s == 2) ? r2 : r3;
        int f = tid + s * 256;
        float yn = -1.f + (float)(f >> 4) * STEP63;
        float xb = (float)((f & 15) * 4);
        float e0 = __expf((r.x - m) * 50.f);
        float e1 = __expf((r.y - m) * 50.f);
        float e2 = __expf((r.z - m) * 50.f);
        float e3 = __expf((r.w - m) * 50.f);
        float es = e0 + e1 + e2 + e3;
        l += es;
        sy += es * yn;
        sx += e0 * (-1.f + xb * STEP63) + e1 * (-1.f + (xb + 1.f) * STEP63)
            + e2 * (-1.f + (xb + 2.f) * STEP63) + e3 * (-1.f + (xb + 3.f) * STEP63);
    }
#pragma unroll
    for (int off = 32; off > 0; off >>= 1) {
        l  += __shfl_xor(l, off, 64);
        sx += __shfl_xor(sx, off, 64);
        sy += __shfl_xor(sy, off, 64);
    }
    if (lane == 0) { red[4 + wave] = l; red[8 + wave] = sx; red[12 + wave] = sy; }
    __syncthreads();
    if (tid == 0) {
        float L  = red[4] + red[5] + red[6] + red[7];
        float SX = red[8] + red[9] + red[10] + red[11];
        float SY = red[12] + red[13] + red[14] + red[15];
        float mx = (SX / L + 1.f) * 31.5f;
        float my = (SY / L + 1.f) * 31.5f;
        int bi = blockIdx.x;
        int b = bi >> 12, p = bi & 4095;
        flow_out[(long long)b * 8192 + p]        = mx - (float)(p & 63);
        flow_out[(long long)b * 8192 + 4096 + p] = my - (float)(p >> 6);
    }
}

// ---------------------------------------------------------------------------
// Output layout (floats): trans_features @0 | coarse @2,097,152 | c @4,194,304
// | c_flip @37,748,736 | flow @71,303,168 | flow_flip @71,319,552
// Fast path stages bf16 hi/lo planes (8 MB) in the trans_features region;
// k_copy_trans rewrites it afterwards (stream-ordered).
// ---------------------------------------------------------------------------
extern "C" void kernel_launch(void* const* d_in, const int* in_sizes, int n_in,
                              void* d_out, int out_size, void* d_ws, size_t ws_size,
                              hipStream_t stream) {
    const float* f0c = (const float*)d_in[0];
    const float* f1c = (const float*)d_in[1];
    const float* f0f = (const float*)d_in[2];
    const float* f1f = (const float*)d_in[3];
    float* out = (float*)d_out;

    float* c_out  = out + 4194304;
    float* cf_out = out + 37748736;
    float* flow   = out + 71303168;
    float* flowf  = out + 71319552;

    if (ws_size >= (size_t)16777216) {
        float* parts = (float*)d_ws;          // 2,097,152 floats (8 MB): softmax partials
        float* cws   = parts + 2097152;       // 2,097,152 floats (8 MB): coarse corr
        unsigned short* hi = (unsigned short*)out;          // 4 planes x [4096][128] bf16
        unsigned short* lo = hi + 2097152;                  // matching lo planes
        k_split<<<dim3(64, 4, 1), 256, 0, stream>>>(f0f, f1f, hi, lo);
        k_corr_c<<<dim3(16, 16, 2), 256, 0, stream>>>(f0c, f1c, cws);
        k_fused2<<<dim3(32, 32, 2), 256, 0, stream>>>(hi, cws, c_out, cf_out, parts);
        k_flow<<<4096, 256, 0, stream>>>(parts, flow, flowf);
        k_copy_trans<<<2048, 256, 0, stream>>>(f0f, f1f, out);   // overwrites plane staging
        k_coarse<<<8192, 256, 0, stream>>>(f0c, f1c, out + 2097152);
    } else {
        float* corr_ws = out;                 // reuse trans_features region as scratch
        k_corr_c<<<dim3(16, 16, 2), 256, 0, stream>>>(f0c, f1c, corr_ws);
        k_fused_fb<<<dim3(64, 64, 2), 256, 0, stream>>>(f0f, f1f, corr_ws, c_out, cf_out);
        k_copy_trans<<<2048, 256, 0, stream>>>(f0f, f1f, out);
        k_coarse<<<8192, 256, 0, stream>>>(f0c, f1c, out + 2097152);
        k_softargmax<<<8192, 256, 0, stream>>>(c_out, flow);
        k_softargmax<<<8192, 256, 0, stream>>>(cf_out, flowf);
    }
}

// Round 6
// 399.269 us; speedup vs baseline: 1.1373x; 1.0219x over previous
//
#include <hip/hip_runtime.h>
#include <math.h>

#define SCALE_C 0.08838834764831845f  // 1/sqrt(128)
#define INV_BETA 50.0f
#define STEP63 (2.0f / 63.0f)

typedef short bf16x8 __attribute__((ext_vector_type(8)));
typedef float f32x4 __attribute__((ext_vector_type(4)));

// align_corners bilinear coefficients for 32 -> 64 (src = t*31/63)
__device__ __forceinline__ void interp_coef32(int t, int& i0, int& i1, float& w) {
    float s = (float)(t * 31) / 63.0f;
    i0 = (int)floorf(s);
    if (i0 > 31) i0 = 31;
    i1 = i0 + 1;
    if (i1 > 31) i1 = 31;
    w = s - (float)i0;
}

// ---------------------------------------------------------------------------
// k_head: blocks [0,256) = k_split (bf16 hi/lo planes); [256,768) = corr_c.
// ---------------------------------------------------------------------------
__global__ __launch_bounds__(256) void k_head(const float* __restrict__ f0f,
                                              const float* __restrict__ f1f,
                                              unsigned short* __restrict__ hi,
                                              unsigned short* __restrict__ lo,
                                              const float* __restrict__ f0c,
                                              const float* __restrict__ f1c,
                                              float* __restrict__ cws) {
    __shared__ unsigned int t[64 * 132];    // split path
    __shared__ float As[16][64];            // corr path
    __shared__ float Bs[16][64];
    const int tid = threadIdx.x;
    if (blockIdx.x < 256) {
        // ---- split: fp32 [mat][128 k][4096 pix] -> bf16 hi/lo [mat][pix][128 k]
        const int m = blockIdx.x >> 6;      // plane: 0,1 = f0f b0,b1; 2,3 = f1f b0,b1
        const int pt = blockIdx.x & 63;     // pixel tile (64 pix)
        const float* src = ((m >> 1) ? f1f : f0f) + (size_t)(m & 1) * 524288 + pt * 64;
#pragma unroll
        for (int p = 0; p < 8; ++p) {
            int k = p * 16 + (tid >> 4);
            int px = (tid & 15) * 4;
            float4 v = *(const float4*)&src[(size_t)k * 4096 + px];
            float vv[4] = {v.x, v.y, v.z, v.w};
#pragma unroll
            for (int j = 0; j < 4; ++j) {
                float x = vv[j];
                unsigned int u = __float_as_uint(x);
                unsigned int h = (u + 0x7FFFu + ((u >> 16) & 1u)) >> 16;     // RNE bf16
                float r = x - __uint_as_float(h << 16);                      // exact
                unsigned int ur = __float_as_uint(r);
                unsigned int l2 = (ur + 0x7FFFu + ((ur >> 16) & 1u)) >> 16;  // RNE bf16
                t[(px + j) * 132 + k] = h | (l2 << 16);
            }
        }
        __syncthreads();
        const int row = tid >> 2, ks = (tid & 3) * 32;
        size_t obase = ((size_t)m * 4096 + (size_t)pt * 64 + row) * 128 + ks;
#pragma unroll
        for (int c = 0; c < 4; ++c) {
            unsigned int u[8];
            *(uint4*)&u[0] = *(const uint4*)&t[row * 132 + ks + c * 8];
            *(uint4*)&u[4] = *(const uint4*)&t[row * 132 + ks + c * 8 + 4];
            uint4 ho, lw;
            ho.x = (u[0] & 0xFFFFu) | (u[1] << 16);
            ho.y = (u[2] & 0xFFFFu) | (u[3] << 16);
            ho.z = (u[4] & 0xFFFFu) | (u[5] << 16);
            ho.w = (u[6] & 0xFFFFu) | (u[7] << 16);
            lw.x = (u[0] >> 16) | (u[1] & 0xFFFF0000u);
            lw.y = (u[2] >> 16) | (u[3] & 0xFFFF0000u);
            lw.z = (u[4] >> 16) | (u[5] & 0xFFFF0000u);
            lw.w = (u[6] >> 16) | (u[7] & 0xFFFF0000u);
            *(uint4*)&hi[obase + c * 8] = ho;
            *(uint4*)&lo[obase + c * 8] = lw;
        }
    } else {
        // ---- corr_c: [b,1024,1024] = f0c^T f1c / sqrt(128). 64x64 tile.
        const int cid = blockIdx.x - 256;
        const int b = cid >> 8;
        const int m0 = ((cid >> 4) & 15) * 64, n0 = (cid & 15) * 64;
        const float* A  = f0c + (long long)b * 131072;
        const float* Bp = f1c + (long long)b * 131072;
        const int tx = tid & 15, ty = tid >> 4;
        const int lk = tid >> 4;
        const int lc = (tid & 15) * 4;
        float acc[4][4] = {{0.f}};
        for (int k0 = 0; k0 < 128; k0 += 16) {
            *(float4*)&As[lk][lc] = *(const float4*)&A[(k0 + lk) * 1024 + m0 + lc];
            *(float4*)&Bs[lk][lc] = *(const float4*)&Bp[(k0 + lk) * 1024 + n0 + lc];
            __syncthreads();
#pragma unroll
            for (int kk = 0; kk < 16; ++kk) {
                float4 a4 = *(float4*)&As[kk][ty * 4];
                float4 b4 = *(float4*)&Bs[kk][tx * 4];
                float av[4] = {a4.x, a4.y, a4.z, a4.w};
                float bv[4] = {b4.x, b4.y, b4.z, b4.w};
#pragma unroll
                for (int i = 0; i < 4; ++i)
#pragma unroll
                    for (int j = 0; j < 4; ++j)
                        acc[i][j] = fmaf(av[i], bv[j], acc[i][j]);
            }
            __syncthreads();
        }
#pragma unroll
        for (int i = 0; i < 4; ++i) {
            float4 w4 = make_float4(acc[i][0] * SCALE_C, acc[i][1] * SCALE_C,
                                    acc[i][2] * SCALE_C, acc[i][3] * SCALE_C);
            *(float4*)&cws[(long long)b * 1048576 + (long long)(m0 + ty * 4 + i) * 1024 + n0 + tx * 4] = w4;
        }
    }
}

// ---------------------------------------------------------------------------
// k_fused2: 128x128 tile of the 4096x4096 GEMM (K=128) via split-bf16 3-pass
// mfma_f32_16x16x32_bf16. 4 waves, each owns a 64x64 sub-tile.
// t2 built by DIRECT gather (round-2 op tree) into [p][x1][x0c] stride 33 —
// LDS total 8448 floats = 33.8 KB so (256,3) actually achieves 3 blocks/CU
// (the 53.76 KB variant silently capped at 2). A-resident/B-streamed GEMM
// keeps peak VGPR ~150 under the 168 cap.
// ---------------------------------------------------------------------------
__global__ __launch_bounds__(256, 3) void k_fused2(const unsigned short* __restrict__ planes,
                                                   const float* __restrict__ cws,
                                                   float* __restrict__ c_out,
                                                   float* __restrict__ cf_out,
                                                   float* __restrict__ parts) {
    __shared__ __attribute__((aligned(16))) float smem[8448];   // t2 | store-stage | pred4
    const int b = blockIdx.z, by = blockIdx.y, bx = blockIdx.x;
    const int tid = threadIdx.x;
    const int wv = tid >> 6, lane = tid & 63;
    const int lr = lane & 15, lq = lane >> 4;
    const int wr = wv >> 1, wc = wv & 1;

    // ---- build t2[p][x1][x0c]: y0/y1/x1-interpolated coarse corr ----
    {
        const float* Cc = cws + (size_t)b * 1048576;
        for (int e = tid; e < 8192; e += 256) {
            int x1 = e & 63, x0c = (e >> 6) & 31, p = e >> 11;
            int s0 = p >> 1, s1 = p & 1;
            int ya, yb; float wy0; interp_coef32(2 * by + s0, ya, yb, wy0);
            int za, zb; float wy1; interp_coef32(2 * bx + s1, za, zb, wy1);
            int xa, xb; float wx1; interp_coef32(x1, xa, xb, wx1);
            const float* r0 = Cc + (size_t)(ya * 32 + x0c) * 1024;
            const float* r1 = Cc + (size_t)(yb * 32 + x0c) * 1024;
            float g0 = (r0[za * 32 + xa] * (1.f - wy1) + r0[zb * 32 + xa] * wy1) * (1.f - wy0)
                     + (r1[za * 32 + xa] * (1.f - wy1) + r1[zb * 32 + xa] * wy1) * wy0;
            float g1 = (r0[za * 32 + xb] * (1.f - wy1) + r0[zb * 32 + xb] * wy1) * (1.f - wy0)
                     + (r1[za * 32 + xb] * (1.f - wy1) + r1[zb * 32 + xb] * wy1) * wy0;
            smem[(p * 64 + x1) * 33 + x0c] = g0 * (1.f - wx1) + g1 * wx1;
        }
    }

    // ---- split-bf16 MFMA GEMM (no LDS involved; A-resident, B-streamed) ----
    const unsigned short* Ah = planes + (size_t)b * 524288       + (size_t)(by * 128 + wr * 64) * 128;
    const unsigned short* Bh = planes + (size_t)(2 + b) * 524288 + (size_t)(bx * 128 + wc * 64) * 128;
    f32x4 acc[4][4];
#pragma unroll
    for (int i = 0; i < 4; ++i)
#pragma unroll
        for (int j = 0; j < 4; ++j) acc[i][j] = (f32x4){0.f, 0.f, 0.f, 0.f};

#pragma unroll 1
    for (int kc = 0; kc < 4; ++kc) {
        const int ko = kc * 32 + lq * 8;
        bf16x8 ah[4], al[4];
#pragma unroll
        for (int t = 0; t < 4; ++t) {
            const unsigned short* pa = Ah + (size_t)(t * 16 + lr) * 128 + ko;
            ah[t] = *(const bf16x8*)pa;
            al[t] = *(const bf16x8*)(pa + 2097152);   // lo planes follow hi planes
        }
#pragma unroll
        for (int ni = 0; ni < 4; ++ni) {
            const unsigned short* pb = Bh + (size_t)(ni * 16 + lr) * 128 + ko;
            bf16x8 bh = *(const bf16x8*)pb;
            bf16x8 bl = *(const bf16x8*)(pb + 2097152);
#pragma unroll
            for (int mi = 0; mi < 4; ++mi) {
                f32x4 a = acc[mi][ni];
                a = __builtin_amdgcn_mfma_f32_16x16x32_bf16(ah[mi], bh, a, 0, 0, 0);
                a = __builtin_amdgcn_mfma_f32_16x16x32_bf16(al[mi], bh, a, 0, 0, 0);
                a = __builtin_amdgcn_mfma_f32_16x16x32_bf16(ah[mi], bl, a, 0, 0, 0);
                acc[mi][ni] = a;
            }
        }
    }

    __syncthreads();   // t2 fully written before epilogue reads

    // ---- epilogue: x0-interp of coarse + combine ----
#pragma unroll
    for (int mi = 0; mi < 4; ++mi)
#pragma unroll
        for (int dr = 0; dr < 4; ++dr) {
            int x0 = mi * 16 + lq * 4 + dr;
            float s = (float)(x0 * 31) / 63.0f;
            int i0 = (int)s;
            float w = s - (float)i0;
            int i1 = i0 + 1; if (i1 > 31) i1 = 31;
#pragma unroll
            for (int ni = 0; ni < 4; ++ni) {
                const float* t2 = &smem[(wv * 64 + ni * 16 + lr) * 33];
                float up = t2[i0] * (1.f - w) + t2[i1] * w;
                acc[mi][ni][dr] = (acc[mi][ni][dr] * SCALE_C + up) * 0.5f;
            }
        }

    // ---- c stores: 2-round LDS transpose -> coalesced float4 rows ----
#pragma unroll
    for (int r = 0; r < 2; ++r) {
        __syncthreads();   // t2/previous-round reads done
        if (wr == r) {
#pragma unroll
            for (int mi = 0; mi < 4; ++mi)
#pragma unroll
                for (int dr = 0; dr < 4; ++dr) {
                    int rl = mi * 16 + lq * 4 + dr;
                    int sw = (rl & 7) << 2;
#pragma unroll
                    for (int ni = 0; ni < 4; ++ni) {
                        int col = wc * 64 + ni * 16 + lr;
                        int c4 = col >> 2;
                        smem[rl * 132 + ((c4 ^ sw) << 2) + (col & 3)] = acc[mi][ni][dr];
                    }
                }
        }
        __syncthreads();
        size_t cb = ((size_t)b << 24) + (size_t)(by * 128 + r * 64) * 4096 + bx * 128;
#pragma unroll
        for (int i = 0; i < 8; ++i) {
            int f = tid + i * 256;          // [0,2048)
            int rl = f >> 5, c4 = f & 31;
            float4 v = *(float4*)&smem[rl * 132 + ((c4 ^ ((rl & 7) << 2)) << 2)];
            *(float4*)&c_out[cb + (size_t)rl * 4096 + c4 * 4] = v;
        }
    }

    // ---- c_flip stores: 2-round LDS transpose (rows of cf = tile cols) ----
#pragma unroll
    for (int r = 0; r < 2; ++r) {
        __syncthreads();   // previous-round reads done
        if (wc == r) {
#pragma unroll
            for (int ni = 0; ni < 4; ++ni) {
                int col = ni * 16 + lr;     // local col within this half
                int sw = (col & 7) << 2;
#pragma unroll
                for (int mi = 0; mi < 4; ++mi) {
                    int q = wr * 16 + mi * 4 + lq;   // row-quad in [0,32)
                    *(float4*)&smem[col * 132 + ((q ^ sw) << 2)] =
                        make_float4(acc[mi][ni][0], acc[mi][ni][1], acc[mi][ni][2], acc[mi][ni][3]);
                }
            }
        }
        __syncthreads();
        size_t fb = ((size_t)b << 24) + (size_t)(bx * 128 + r * 64) * 4096 + by * 128;
#pragma unroll
        for (int i = 0; i < 8; ++i) {
            int f = tid + i * 256;          // [0,2048)
            int col = f >> 5, q = f & 31;
            float4 v = *(float4*)&smem[col * 132 + ((q ^ ((col & 7) << 2)) << 2)];
            *(float4*)&cf_out[fb + (size_t)col * 4096 + q * 4] = v;
        }
    }

    // ---- softmax partials ----
    float4* pred4 = (float4*)smem;
    float4* parts4 = (float4*)parts;
    __syncthreads();   // transpose reads done; reuse LDS as pred4

    // c-direction: per row, reduce over this wave's 64 cols (lanes sharing lq)
    {
        float yn1 = -1.f + (float)(2 * bx + wc) * STEP63;
#pragma unroll
        for (int mi = 0; mi < 4; ++mi)
#pragma unroll
            for (int dr = 0; dr < 4; ++dr) {
                float m = fmaxf(fmaxf(acc[mi][0][dr], acc[mi][1][dr]),
                                fmaxf(acc[mi][2][dr], acc[mi][3][dr]));
                m = fmaxf(m, __shfl_xor(m, 1, 64));
                m = fmaxf(m, __shfl_xor(m, 2, 64));
                m = fmaxf(m, __shfl_xor(m, 4, 64));
                m = fmaxf(m, __shfl_xor(m, 8, 64));
                float l = 0.f, sx = 0.f;
#pragma unroll
                for (int ni = 0; ni < 4; ++ni) {
                    float e = __expf((acc[mi][ni][dr] - m) * INV_BETA);
                    l += e;
                    sx += e * (-1.f + (float)(ni * 16 + lr) * STEP63);
                }
                l += __shfl_xor(l, 1, 64);  sx += __shfl_xor(sx, 1, 64);
                l += __shfl_xor(l, 2, 64);  sx += __shfl_xor(sx, 2, 64);
                l += __shfl_xor(l, 4, 64);  sx += __shfl_xor(sx, 4, 64);
                l += __shfl_xor(l, 8, 64);  sx += __shfl_xor(sx, 8, 64);
                if (lr == 0)
                    pred4[wc * 128 + wr * 64 + mi * 16 + lq * 4 + dr] = make_float4(m, l, sx, yn1 * l);
            }
    }
    __syncthreads();
    if (tid < 128) {
        float4 h0 = pred4[tid], h1 = pred4[128 + tid];
        float M = fmaxf(h0.x, h1.x);
        float s0 = __expf((h0.x - M) * INV_BETA);
        float s1 = __expf((h1.x - M) * INV_BETA);
        parts4[((size_t)b * 4096 + by * 128 + tid) * 32 + bx] =
            make_float4(M, h0.y * s0 + h1.y * s1, h0.z * s0 + h1.z * s1, h0.w * s0 + h1.w * s1);
    }
    __syncthreads();

    // f-direction: per col, reduce over this wave's 64 rows (lanes sharing lr)
    {
        float yn0 = -1.f + (float)(2 * by + wr) * STEP63;
#pragma unroll
        for (int ni = 0; ni < 4; ++ni) {
            float m = acc[0][ni][0];
#pragma unroll
            for (int mi = 0; mi < 4; ++mi)
#pragma unroll
                for (int dr = 0; dr < 4; ++dr) m = fmaxf(m, acc[mi][ni][dr]);
            m = fmaxf(m, __shfl_xor(m, 16, 64));
            m = fmaxf(m, __shfl_xor(m, 32, 64));
            float l = 0.f, sx = 0.f;
#pragma unroll
            for (int mi = 0; mi < 4; ++mi)
#pragma unroll
                for (int dr = 0; dr < 4; ++dr) {
                    float e = __expf((acc[mi][ni][dr] - m) * INV_BETA);
                    l += e;
                    sx += e * (-1.f + (float)(mi * 16 + lq * 4 + dr) * STEP63);
                }
            l += __shfl_xor(l, 16, 64);  sx += __shfl_xor(sx, 16, 64);
            l += __shfl_xor(l, 32, 64);  sx += __shfl_xor(sx, 32, 64);
            if (lq == 0)
                pred4[wr * 128 + wc * 64 + ni * 16 + lr] = make_float4(m, l, sx, yn0 * l);
        }
    }
    __syncthreads();
    if (tid < 128) {
        float4 h0 = pred4[tid], h1 = pred4[128 + tid];
        float M = fmaxf(h0.x, h1.x);
        float s0 = __expf((h0.x - M) * INV_BETA);
        float s1 = __expf((h1.x - M) * INV_BETA);
        parts4[262144 + ((size_t)b * 4096 + bx * 128 + tid) * 32 + by] =
            make_float4(M, h0.y * s0 + h1.y * s1, h0.z * s0 + h1.z * s1, h0.w * s0 + h1.w * s1);
    }
}

// ---------------------------------------------------------------------------
// k_tail: blocks [0,4096) = flow-merge; [4096,6144) = copy_trans;
// [6144,14336) = coarse upsample.
// ---------------------------------------------------------------------------
__global__ __launch_bounds__(256) void k_tail(const float* __restrict__ parts,
                                              float* __restrict__ flow,
                                              float* __restrict__ flowf,
                                              const float* __restrict__ f0f,
                                              const float* __restrict__ f1f,
                                              float* __restrict__ out1,
                                              const float* __restrict__ f0c,
                                              const float* __restrict__ f1c,
                                              float* __restrict__ out2) {
    const int bid = blockIdx.x;
    const int tid = threadIdx.x;
    if (bid < 4096) {
        // ---- flow: merge 32 partials per row. One wave per row. ----
        const int row = bid * 4 + (tid >> 6);
        const int lane = tid & 63;
        const float4* p4 = (const float4*)parts + (long long)row * 32;
        float m = -1e30f, l = 0.f, sx = 0.f, sy = 0.f;
        if (lane < 32) { float4 v = p4[lane]; m = v.x; l = v.y; sx = v.z; sy = v.w; }
        float M = m;
#pragma unroll
        for (int off = 1; off < 64; off <<= 1) M = fmaxf(M, __shfl_xor(M, off, 64));
        float s = __expf((m - M) * INV_BETA);
        l *= s; sx *= s; sy *= s;
#pragma unroll
        for (int off = 1; off < 64; off <<= 1) {
            l += __shfl_xor(l, off, 64);
            sx += __shfl_xor(sx, off, 64);
            sy += __shfl_xor(sy, off, 64);
        }
        if (lane == 0) {
            float gx = sx / l, gy = sy / l;
            float mx = (gx + 1.f) * 31.5f, my = (gy + 1.f) * 31.5f;
            int dir = row >> 13, b = (row >> 12) & 1, p = row & 4095;
            float* o = dir ? flowf : flow;
            o[(long long)b * 8192 + p] = mx - (float)(p & 63);
            o[(long long)b * 8192 + 4096 + p] = my - (float)(p >> 6);
        }
    } else if (bid < 6144) {
        // ---- trans_features = stack([f0f, f1f], axis=1) ----
        int idx = (bid - 4096) * 256 + tid;
        int bv = idx >> 17;
        int r = idx & 131071;
        int b = bv >> 1, v = bv & 1;
        const float4* src = (const float4*)(v ? f1f : f0f) + (long long)b * 131072 + r;
        ((float4*)out1)[idx] = *src;
    } else {
        // ---- trans_features_coarse: bilinear 32->64 of stacked feat_c ----
        int idx = (bid - 6144) * 256 + tid;
        int x = idx & 63, y = (idx >> 6) & 63, ch = (idx >> 12) & 127;
        int v = (idx >> 19) & 1, b = idx >> 20;
        int iy0, iy1; float wy; interp_coef32(y, iy0, iy1, wy);
        int ix0, ix1; float wx; interp_coef32(x, ix0, ix1, wx);
        const float* src = (v ? f1c : f0c) + (long long)(b * 128 + ch) * 1024;
        float a  = src[iy0 * 32 + ix0] * (1.f - wy) + src[iy1 * 32 + ix0] * wy;
        float c2 = src[iy0 * 32 + ix1] * (1.f - wy) + src[iy1 * 32 + ix1] * wy;
        out2[idx] = a * (1.f - wx) + c2 * wx;
    }
}

// ========================= fallback-path kernels ===========================
__global__ __launch_bounds__(256) void k_corr_c(const float* __restrict__ f0c,
                                                const float* __restrict__ f1c,
                                                float* __restrict__ ws) {
    __shared__ float As[16][64];
    __shared__ float Bs[16][64];
    const int b = blockIdx.z;
    const int m0 = blockIdx.y * 64, n0 = blockIdx.x * 64;
    const float* A  = f0c + (long long)b * 131072;
    const float* Bp = f1c + (long long)b * 131072;
    const int tid = threadIdx.x;
    const int tx = tid & 15, ty = tid >> 4;
    const int lk = tid >> 4;
    const int lc = (tid & 15) * 4;
    float acc[4][4] = {{0.f}};
    for (int k0 = 0; k0 < 128; k0 += 16) {
        *(float4*)&As[lk][lc] = *(const float4*)&A[(k0 + lk) * 1024 + m0 + lc];
        *(float4*)&Bs[lk][lc] = *(const float4*)&Bp[(k0 + lk) * 1024 + n0 + lc];
        __syncthreads();
#pragma unroll
        for (int kk = 0; kk < 16; ++kk) {
            float4 a4 = *(float4*)&As[kk][ty * 4];
            float4 b4 = *(float4*)&Bs[kk][tx * 4];
            float av[4] = {a4.x, a4.y, a4.z, a4.w};
            float bv[4] = {b4.x, b4.y, b4.z, b4.w};
#pragma unroll
            for (int i = 0; i < 4; ++i)
#pragma unroll
                for (int j = 0; j < 4; ++j)
                    acc[i][j] = fmaf(av[i], bv[j], acc[i][j]);
        }
        __syncthreads();
    }
#pragma unroll
    for (int i = 0; i < 4; ++i) {
        float4 w4 = make_float4(acc[i][0] * SCALE_C, acc[i][1] * SCALE_C,
                                acc[i][2] * SCALE_C, acc[i][3] * SCALE_C);
        *(float4*)&ws[(long long)b * 1048576 + (long long)(m0 + ty * 4 + i) * 1024 + n0 + tx * 4] = w4;
    }
}

__global__ void k_copy_trans(const float* __restrict__ f0f, const float* __restrict__ f1f,
                             float* __restrict__ out1) {
    int idx = blockIdx.x * 256 + threadIdx.x;
    int bv = idx >> 17;
    int r = idx & 131071;
    int b = bv >> 1, v = bv & 1;
    const float4* src = (const float4*)(v ? f1f : f0f) + (long long)b * 131072 + r;
    ((float4*)out1)[idx] = *src;
}

__global__ void k_coarse(const float* __restrict__ f0c, const float* __restrict__ f1c,
                         float* __restrict__ out2) {
    int idx = blockIdx.x * 256 + threadIdx.x;
    int x = idx & 63, y = (idx >> 6) & 63, ch = (idx >> 12) & 127;
    int v = (idx >> 19) & 1, b = idx >> 20;
    int iy0, iy1; float wy; interp_coef32(y, iy0, iy1, wy);
    int ix0, ix1; float wx; interp_coef32(x, ix0, ix1, wx);
    const float* src = (v ? f1c : f0c) + (long long)(b * 128 + ch) * 1024;
    float a  = src[iy0 * 32 + ix0] * (1.f - wy) + src[iy1 * 32 + ix0] * wy;
    float c2 = src[iy0 * 32 + ix1] * (1.f - wy) + src[iy1 * 32 + ix1] * wy;
    out2[idx] = a * (1.f - wx) + c2 * wx;
}

__global__ __launch_bounds__(256) void k_fused_fb(const float* __restrict__ f0f,
                                                  const float* __restrict__ f1f,
                                                  const float* __restrict__ cws,
                                                  float* __restrict__ c_out,
                                                  float* __restrict__ cf_out) {
    __shared__ float As[16][64];
    __shared__ float Bs[16][64];
    __shared__ float tmp[32][33];
    const int b = blockIdx.z, y0 = blockIdx.y, y1 = blockIdx.x;
    const int tid = threadIdx.x;
    const int tx = tid & 15, ty = tid >> 4;
    const float* A  = f0f + (long long)b * 524288 + y0 * 64;
    const float* Bp = f1f + (long long)b * 524288 + y1 * 64;
    int iy0a, iy0b; float wy0; interp_coef32(y0, iy0a, iy0b, wy0);
    int iy1a, iy1b; float wy1; interp_coef32(y1, iy1a, iy1b, wy1);
    const float* Cc = cws + (long long)b * 1048576;
    for (int r = tid; r < 1024; r += 256) {
        int i = r >> 5, j = r & 31;
        const float* ra = Cc + (long long)(iy0a * 32 + i) * 1024;
        const float* rb = Cc + (long long)(iy0b * 32 + i) * 1024;
        float va = ra[iy1a * 32 + j] * (1.f - wy1) + ra[iy1b * 32 + j] * wy1;
        float vb = rb[iy1a * 32 + j] * (1.f - wy1) + rb[iy1b * 32 + j] * wy1;
        tmp[i][j] = va * (1.f - wy0) + vb * wy0;
    }
    float acc[4][4] = {{0.f}};
    const int lk = tid >> 4;
    const int lc = (tid & 15) * 4;
    for (int k0 = 0; k0 < 128; k0 += 16) {
        *(float4*)&As[lk][lc] = *(const float4*)&A[(long long)(k0 + lk) * 4096 + lc];
        *(float4*)&Bs[lk][lc] = *(const float4*)&Bp[(long long)(k0 + lk) * 4096 + lc];
        __syncthreads();
#pragma unroll
        for (int kk = 0; kk < 16; ++kk) {
            float4 a4 = *(float4*)&As[kk][ty * 4];
            float4 b4 = *(float4*)&Bs[kk][tx * 4];
            float av[4] = {a4.x, a4.y, a4.z, a4.w};
            float bv[4] = {b4.x, b4.y, b4.z, b4.w};
#pragma unroll
            for (int i = 0; i < 4; ++i)
#pragma unroll
                for (int j = 0; j < 4; ++j)
                    acc[i][j] = fmaf(av[i], bv[j], acc[i][j]);
        }
        __syncthreads();
    }
    int ix0a[4], ix0b[4]; float wx0[4];
    int ix1a[4], ix1b[4]; float wx1[4];
#pragma unroll
    for (int i = 0; i < 4; ++i) interp_coef32(ty * 4 + i, ix0a[i], ix0b[i], wx0[i]);
#pragma unroll
    for (int j = 0; j < 4; ++j) interp_coef32(tx * 4 + j, ix1a[j], ix1b[j], wx1[j]);
    float val[4][4];
#pragma unroll
    for (int i = 0; i < 4; ++i)
#pragma unroll
        for (int j = 0; j < 4; ++j) {
            float ta = tmp[ix0a[i]][ix1a[j]] * (1.f - wx1[j]) + tmp[ix0a[i]][ix1b[j]] * wx1[j];
            float tb = tmp[ix0b[i]][ix1a[j]] * (1.f - wx1[j]) + tmp[ix0b[i]][ix1b[j]] * wx1[j];
            val[i][j] = (acc[i][j] * SCALE_C + (ta * (1.f - wx0[i]) + tb * wx0[i])) * 0.5f;
        }
    const long long cbase = ((long long)b << 24) + (long long)(y0 * 64) * 4096 + y1 * 64;
#pragma unroll
    for (int i = 0; i < 4; ++i)
        *(float4*)&c_out[cbase + (long long)(ty * 4 + i) * 4096 + tx * 4] =
            make_float4(val[i][0], val[i][1], val[i][2], val[i][3]);
    const long long fbase = ((long long)b << 24) + (long long)(y1 * 64) * 4096 + y0 * 64;
#pragma unroll
    for (int j = 0; j < 4; ++j)
        *(float4*)&cf_out[fbase + (long long)(tx * 4 + j) * 4096 + ty * 4] =
            make_float4(val[0][j], val[1][j], val[2][j], val[3][j]);
}

__global__ __launch_bounds__(256) void k_softargmax(const float* __restrict__ cmat,
                                                    float* __restrict__ flow_out) {
    const int tid = threadIdx.x;
    const float4* src = (const float4*)cmat + (long long)blockIdx.x * 1024;
    float4 r0 = src[tid];
    float4 r1 = src[tid + 256];
    float4 r2 = src[tid + 512];
    float4 r3 = src[tid + 768];
    float m = fmaxf(fmaxf(fmaxf(r0.x, r0.y), fmaxf(r0.z, r0.w)),
                    fmaxf(fmaxf(r1.x, r1.y), fmaxf(r1.z, r1.w)));
    m = fmaxf(m, fmaxf(fmaxf(r2.x, r2.y), fmaxf(r2.z, r2.w)));
    m = fmaxf(m, fmaxf(fmaxf(r3.x, r3.y), fmaxf(r3.z, r3.w)));
    __shared__ float red[16];
    const int lane = tid & 63, wave = tid >> 6;
#pragma unroll
    for (int off = 32; off > 0; off >>= 1) m = fmaxf(m, __shfl_xor(m, off, 64));
    if (lane == 0) red[wave] = m;
    __syncthreads();
    m = fmaxf(fmaxf(red[0], red[1]), fmaxf(red[2], red[3]));
    float l = 0.f, sx = 0.f, sy = 0.f;
#pragma unroll
    for (int s = 0; s < 4; ++s) {
        float4 r = (s == 0) ? r0 : (s == 1) ? r1 : (s == 2) ? r2 : r3;
        int f = tid + s * 256;
        float yn = -1.f + (float)(f >> 4) * STEP63;
        float xb = (float)((f & 15) * 4);
        float e0 = __expf((r.x - m) * 50.f);
        float e1 = __expf((r.y - m) * 50.f);
        float e2 = __expf((r.z - m) * 50.f);
        float e3 = __expf((r.w - m) * 50.f);
        float es = e0 + e1 + e2 + e3;
        l += es;
        sy += es * yn;
        sx += e0 * (-1.f + xb * STEP63) + e1 * (-1.f + (xb + 1.f) * STEP63)
            + e2 * (-1.f + (xb + 2.f) * STEP63) + e3 * (-1.f + (xb + 3.f) * STEP63);
    }
#pragma unroll
    for (int off = 32; off > 0; off >>= 1) {
        l  += __shfl_xor(l, off, 64);
        sx += __shfl_xor(sx, off, 64);
        sy += __shfl_xor(sy, off, 64);
    }
    if (lane == 0) { red[4 + wave] = l; red[8 + wave] = sx; red[12 + wave] = sy; }
    __syncthreads();
    if (tid == 0) {
        float L  = red[4] + red[5] + red[6] + red[7];
        float SX = red[8] + red[9] + red[10] + red[11];
        float SY = red[12] + red[13] + red[14] + red[15];
        float mx = (SX / L + 1.f) * 31.5f;
        float my = (SY / L + 1.f) * 31.5f;
        int bi = blockIdx.x;
        int b = bi >> 12, p = bi & 4095;
        flow_out[(long long)b * 8192 + p]        = mx - (float)(p & 63);
        flow_out[(long long)b * 8192 + 4096 + p] = my - (float)(p >> 6);
    }
}

// ---------------------------------------------------------------------------
// Output layout (floats): trans_features @0 | coarse @2,097,152 | c @4,194,304
// | c_flip @37,748,736 | flow @71,303,168 | flow_flip @71,319,552
// Fast path stages bf16 hi/lo planes (16 MB) in the trans_features region;
// k_tail's copy path rewrites it afterwards (stream-ordered).
// ---------------------------------------------------------------------------
extern "C" void kernel_launch(void* const* d_in, const int* in_sizes, int n_in,
                              void* d_out, int out_size, void* d_ws, size_t ws_size,
                              hipStream_t stream) {
    const float* f0c = (const float*)d_in[0];
    const float* f1c = (const float*)d_in[1];
    const float* f0f = (const float*)d_in[2];
    const float* f1f = (const float*)d_in[3];
    float* out = (float*)d_out;

    float* c_out  = out + 4194304;
    float* cf_out = out + 37748736;
    float* flow   = out + 71303168;
    float* flowf  = out + 71319552;

    if (ws_size >= (size_t)16777216) {
        float* parts = (float*)d_ws;          // 2,097,152 floats (8 MB): softmax partials
        float* cws   = parts + 2097152;       // 2,097,152 floats (8 MB): coarse corr
        unsigned short* hi = (unsigned short*)out;          // 4 planes x [4096][128] bf16
        unsigned short* lo = hi + 2097152;                  // matching lo planes
        k_head<<<768, 256, 0, stream>>>(f0f, f1f, hi, lo, f0c, f1c, cws);
        k_fused2<<<dim3(32, 32, 2), 256, 0, stream>>>(hi, cws, c_out, cf_out, parts);
        k_tail<<<14336, 256, 0, stream>>>(parts, flow, flowf, f0f, f1f, out, f0c, f1c, out + 2097152);
    } else {
        float* corr_ws = out;                 // reuse trans_features region as scratch
        k_corr_c<<<dim3(16, 16, 2), 256, 0, stream>>>(f0c, f1c, corr_ws);
        k_fused_fb<<<dim3(64, 64, 2), 256, 0, stream>>>(f0f, f1f, corr_ws, c_out, cf_out);
        k_copy_trans<<<2048, 256, 0, stream>>>(f0f, f1f, out);
        k_coarse<<<8192, 256, 0, stream>>>(f0c, f1c, out + 2097152);
        k_softargmax<<<8192, 256, 0, stream>>>(c_out, flow);
        k_softargmax<<<8192, 256, 0, stream>>>(cf_out, flowf);
    }
}